// Round 14
// baseline (304.930 us; speedup 1.0000x reference)
//
#include <hip/hip_runtime.h>
#include <hip/hip_bf16.h>

#define NROWS 8192
#define DIM 512
#define NSLOT 132  // row-side 68 (17s x 2nh x 2g) + col-side 64 (16s x 2h x 2m)
#define KMASK 0xFFFFE000u  // top-19 key bits; low 13 = index

typedef __attribute__((ext_vector_type(8))) short bf16x8;
typedef __attribute__((ext_vector_type(4))) float f32x4;
typedef __attribute__((ext_vector_type(8))) unsigned short u16x8;

__device__ __forceinline__ float bf2f(unsigned short u) {
    return __uint_as_float(((unsigned int)u) << 16);
}
__device__ __forceinline__ unsigned short f2bf(float f) {
    unsigned int b = __float_as_uint(f);
    return (unsigned short)((b + 0x7FFFu + ((b >> 16) & 1u)) >> 16);
}
// monotone float->uint key: a<b <=> fkey(a)<fkey(b)
__device__ __forceinline__ unsigned int fkey(float f) {
    unsigned int b = __float_as_uint(f);
    return (b & 0x80000000u) ? ~b : (b | 0x80000000u);
}
__device__ __forceinline__ float unfkey(unsigned int u) {
    unsigned int b = (u & 0x80000000u) ? (u ^ 0x80000000u) : ~u;
    return __uint_as_float(b);
}
__device__ __forceinline__ unsigned int minu(unsigned int a, unsigned int b) {
    return a < b ? a : b;
}
__device__ __forceinline__ unsigned long long min64(unsigned long long a,
                                                    unsigned long long b) {
    return a < b ? a : b;
}

// ---------------------------------------------------------------- k_prep
__global__ __launch_bounds__(256) void k_prep(const float* __restrict__ xs,
                                              unsigned short* __restrict__ hi,
                                              float* __restrict__ sq) {
    const int wave = threadIdx.x >> 6, lane = threadIdx.x & 63;
    const int row = blockIdx.x * 4 + wave;
    const float4* xr = (const float4*)(xs + (size_t)row * DIM);
    const float4 a = xr[2 * lane], b = xr[2 * lane + 1];
    float v[8] = {a.x, a.y, a.z, a.w, b.x, b.y, b.z, b.w};
    u16x8 h;
    float s = 0.f;
#pragma unroll
    for (int i = 0; i < 8; ++i) {
        h[i] = f2bf(v[i]);
        s = fmaf(v[i], v[i], s);
    }
    *(u16x8*)(hi + (size_t)row * DIM + lane * 8) = h;
#pragma unroll
    for (int d = 32; d; d >>= 1) s += __shfl_xor(s, d);
    if (lane == 0) sq[row] = s;
}

// ---------------------------------------------------------------- k_nn
// 128(i) x 256(j) blocks over a 32x32 triangle of 256-row supertiles.
// b -> xcd=b&7, w=b>>3: h=w&1 (i 128-half), ul=(w>>1)&3, s=w>>3 (0..16);
// u=xcd*4+ul, v=(u+s)&31; i0=u*256+h*128, j0=v*256.
// DMA double-buffered staging (24 stripes of 16 rows: 8 A + 16 B, 6/wave),
// swizzled layout, acc 4x8/wave, u32 top-2 epilogue (row groups of 64 j).
__global__ __launch_bounds__(256) void k_nn(const unsigned short* __restrict__ xh,
                                            const float* __restrict__ sq,
                                            unsigned int* __restrict__ rowtab) {
    __shared__ __align__(16) unsigned short lds[2 * 12288];  // buf: [A 4096 | B 8192]
    const int tid = threadIdx.x;
    const int wave = tid >> 6, lane = tid & 63, quad = lane >> 4, ln = lane & 15;
    const int b = blockIdx.x;
    const int xcd = b & 7, w = b >> 3;
    const int h = w & 1, ul = (w >> 1) & 3, s = w >> 3;
    const int u = xcd * 4 + ul, v = (u + s) & 31;
    const int i0 = u * 256 + h * 128;
    const int j0 = v * 256;
    const int m_off = (wave & 1) * 64, n_off = (wave >> 1) * 128;

    // staging: 24 stripes (t<8: A rows i0+t*16; t>=8: B rows j0+(t-8)*16)
    const int rl = lane >> 2;
    const int cc = ((lane & 3) - (rl >> 1)) & 3;
    const unsigned short* gp[6];
    int lofs[6];
#pragma unroll
    for (int i = 0; i < 6; ++i) {
        const int t = wave * 6 + i;
        const int rowb = (t < 8) ? (i0 + t * 16) : (j0 + (t - 8) * 16);
        gp[i] = xh + (size_t)(rowb + rl) * DIM + cc * 8;
        lofs[i] = (t < 8) ? t * 512 : 4096 + (t - 8) * 512;
    }

    int aoff[4], boff[8];
#pragma unroll
    for (int ms = 0; ms < 4; ++ms) {
        const int r = m_off + ms * 16 + ln;
        aoff[ms] = r * 32 + ((quad + (r >> 1)) & 3) * 8;
    }
#pragma unroll
    for (int ns = 0; ns < 8; ++ns) {
        const int r = n_off + ns * 16 + ln;
        boff[ns] = 4096 + r * 32 + ((quad + (r >> 1)) & 3) * 8;
    }

    f32x4 acc[4][8];
#pragma unroll
    for (int a = 0; a < 4; ++a)
#pragma unroll
        for (int c = 0; c < 8; ++c) acc[a][c] = (f32x4){0.f, 0.f, 0.f, 0.f};

    // preload kt=0 into buf0
#pragma unroll
    for (int i = 0; i < 6; ++i)
        __builtin_amdgcn_global_load_lds(
            (const __attribute__((address_space(1))) void*)gp[i],
            (__attribute__((address_space(3))) void*)(lds + lofs[i]), 16, 0, 0);

    for (int kt = 0; kt < 16; ++kt) {
        __syncthreads();  // drains DMA filling buf[kt&1]; prior reads done
        const int cur = (kt & 1) * 12288;
        if (kt < 15) {
            const int nxt = ((kt + 1) & 1) * 12288;
            const int ko = (kt + 1) * 32;
#pragma unroll
            for (int i = 0; i < 6; ++i)
                __builtin_amdgcn_global_load_lds(
                    (const __attribute__((address_space(1))) void*)(gp[i] + ko),
                    (__attribute__((address_space(3))) void*)(lds + nxt + lofs[i]),
                    16, 0, 0);
        }
        bf16x8 ah[4];
#pragma unroll
        for (int ms = 0; ms < 4; ++ms) ah[ms] = *(const bf16x8*)(lds + cur + aoff[ms]);
#pragma unroll
        for (int ns = 0; ns < 8; ++ns) {
            const bf16x8 bh = *(const bf16x8*)(lds + cur + boff[ns]);
#pragma unroll
            for (int ms = 0; ms < 4; ++ms)
                acc[ms][ns] = __builtin_amdgcn_mfma_f32_16x16x32_bf16(
                    ah[ms], bh, acc[ms][ns], 0, 0, 0);
        }
    }

    // ---- epilogue: u32-packed top-2 ----
    const bool diag = (s == 0);
    float sqj[8];
#pragma unroll
    for (int ns = 0; ns < 8; ++ns) sqj[ns] = sq[j0 + n_off + ns * 16 + ln];
    float sqi[4][4];
#pragma unroll
    for (int ms = 0; ms < 4; ++ms)
#pragma unroll
        for (int vv = 0; vv < 4; ++vv)
            sqi[ms][vv] = sq[i0 + m_off + ms * 16 + quad * 4 + vv];

    // row-side: per i-row, top-2 per 64-j sub-group (g=0: ns 0-3, g=1: ns 4-7)
#pragma unroll
    for (int ms = 0; ms < 4; ++ms)
#pragma unroll
        for (int vv = 0; vv < 4; ++vv) {
            const int gi = i0 + m_off + ms * 16 + quad * 4 + vv;
#pragma unroll
            for (int g = 0; g < 2; ++g) {
                unsigned int pk[4];
#pragma unroll
                for (int n4 = 0; n4 < 4; ++n4) {
                    const int ns = g * 4 + n4;
                    const int gj = j0 + n_off + ns * 16 + ln;
                    float d2 = fmaf(-2.f, acc[ms][ns][vv], sqj[ns]);
                    if (diag && gj == gi) d2 = __builtin_inff();
                    pk[n4] = (fkey(d2) & KMASK) | (unsigned int)gj;
                }
                unsigned int m1 = minu(minu(pk[0], pk[1]), minu(pk[2], pk[3]));
#pragma unroll
                for (int d = 1; d < 16; d <<= 1) m1 = minu(m1, __shfl_xor(m1, d));
                unsigned int m2 = 0xFFFFFFFFu;
#pragma unroll
                for (int n4 = 0; n4 < 4; ++n4)
                    m2 = minu(m2, pk[n4] == m1 ? 0xFFFFFFFFu : pk[n4]);
#pragma unroll
                for (int d = 1; d < 16; d <<= 1) m2 = minu(m2, __shfl_xor(m2, d));
                if (ln == 0) {
                    const int slot = s * 4 + (wave >> 1) * 2 + g;
                    const size_t base = ((size_t)gi * NSLOT + slot) * 2;
                    rowtab[base] = m1;
                    rowtab[base + 1] = m2;
                }
            }
        }
    // col-side: per j-col, top-2 over this wave's 64 i-rows (skip s==0)
    if (s > 0) {
#pragma unroll
        for (int ns = 0; ns < 8; ++ns) {
            const int gj = j0 + n_off + ns * 16 + ln;
            unsigned int pk[16];
#pragma unroll
            for (int ms = 0; ms < 4; ++ms)
#pragma unroll
                for (int vv = 0; vv < 4; ++vv) {
                    const int gi = i0 + m_off + ms * 16 + quad * 4 + vv;
                    const float d2 = fmaf(-2.f, acc[ms][ns][vv], sqi[ms][vv]);
                    pk[ms * 4 + vv] = (fkey(d2) & KMASK) | (unsigned int)gi;
                }
            unsigned int m1 = pk[0];
#pragma unroll
            for (int t = 1; t < 16; ++t) m1 = minu(m1, pk[t]);
            m1 = minu(m1, __shfl_xor(m1, 16));
            m1 = minu(m1, __shfl_xor(m1, 32));
            unsigned int m2 = 0xFFFFFFFFu;
#pragma unroll
            for (int t = 0; t < 16; ++t)
                m2 = minu(m2, pk[t] == m1 ? 0xFFFFFFFFu : pk[t]);
            m2 = minu(m2, __shfl_xor(m2, 16));
            m2 = minu(m2, __shfl_xor(m2, 32));
            if (quad == 0) {
                const int slot = 68 + (s - 1) * 4 + h * 2 + (wave & 1);
                const size_t base = ((size_t)gj * NSLOT + slot) * 2;
                rowtab[base] = m1;
                rowtab[base + 1] = m2;
            }
        }
    }
}

// ---------------------------------------------------------------- k_refine
// Wave per row: global min over 264 u32 entries, candidates within margin 4.0,
// exact fp32 np-style d2 recompute, lexicographic min.
__global__ __launch_bounds__(256) void k_refine(const unsigned int* __restrict__ rowtab,
                                                const float* __restrict__ xs,
                                                const float* __restrict__ sq,
                                                unsigned long long* __restrict__ nn) {
    __shared__ unsigned int clist[4][64];
    __shared__ int ccnt[4];
    const int wave = threadIdx.x >> 6, lane = threadIdx.x & 63;
    const int row = blockIdx.x * 4 + wave;
    if (lane == 0) ccnt[wave] = 0;
    __syncthreads();

    unsigned int vals[5];
    int nv = 0;
    unsigned int best = 0xFFFFFFFFu;
    for (int i = lane; i < NSLOT * 2; i += 64) {
        const unsigned int v = rowtab[(size_t)row * NSLOT * 2 + i];
        vals[nv++] = v;
        best = minu(best, v);
    }
#pragma unroll
    for (int d = 1; d < 64; d <<= 1) best = minu(best, __shfl_xor(best, d));

    const float dmin = unfkey(best & KMASK);
    const unsigned int tkey = fkey(dmin + 4.0f);
    for (int k = 0; k < nv; ++k)
        if ((vals[k] & KMASK) < tkey) {
            const int p = atomicAdd(&ccnt[wave], 1);
            if (p < 64) clist[wave][p] = vals[k] & 8191u;
        }
    __syncthreads();
    int cnt = ccnt[wave];
    cnt = cnt > 64 ? 64 : cnt;

    const float4* xi = (const float4*)(xs + (size_t)row * DIM);
    const float4 x0 = xi[2 * lane], x1 = xi[2 * lane + 1];
    const float sqi = sq[row];
    unsigned long long bestf = ~0ull;
    for (int c = 0; c < cnt; ++c) {
        const unsigned int j = clist[wave][c];
        const float4* xj = (const float4*)(xs + (size_t)j * DIM);
        const float4 y0 = xj[2 * lane], y1 = xj[2 * lane + 1];
        float dot = 0.f;
        dot = fmaf(x0.x, y0.x, dot); dot = fmaf(x0.y, y0.y, dot);
        dot = fmaf(x0.z, y0.z, dot); dot = fmaf(x0.w, y0.w, dot);
        dot = fmaf(x1.x, y1.x, dot); dot = fmaf(x1.y, y1.y, dot);
        dot = fmaf(x1.z, y1.z, dot); dot = fmaf(x1.w, y1.w, dot);
#pragma unroll
        for (int d = 1; d < 64; d <<= 1) dot += __shfl_xor(dot, d);
        const float d2 = sqi + sq[j] - 2.f * dot;
        const unsigned long long pk = (((unsigned long long)fkey(d2)) << 32) | j;
        bestf = min64(bestf, pk);
    }
    if (lane == 0) nn[row] = bestf;
}

// helpers for tail GEMMs
__device__ __forceinline__ void split3(const float* v, u16x8& h8, u16x8& m8, u16x8& l8) {
#pragma unroll
    for (int j = 0; j < 8; ++j) {
        const float x = v[j];
        const unsigned short h = f2bf(x);
        const float r1 = x - bf2f(h);
        const unsigned short m = f2bf(r1);
        const float r2 = r1 - bf2f(m);
        h8[j] = h; m8[j] = m; l8[j] = f2bf(r2);
    }
}
__device__ __forceinline__ void split2(const float* v, u16x8& h8, u16x8& l8) {
#pragma unroll
    for (int j = 0; j < 8; ++j) {
        const float x = v[j];
        const unsigned short h = f2bf(x);
        h8[j] = h; l8[j] = f2bf(x - bf2f(h));
    }
}

// ---------------------------------------------------------------- k_p  (unchanged)
__global__ __launch_bounds__(256) void k_p(const float* __restrict__ xs,
                                           const float* __restrict__ W1,
                                           float* __restrict__ P) {
    __shared__ __align__(16) unsigned short lAh[64 * 32], lAm[64 * 32], lAl[64 * 32];
    __shared__ __align__(16) unsigned short lWh[64 * 32], lWm[64 * 32], lWl[64 * 32];
    const int tid = threadIdx.x, wave = tid >> 6, lane = tid & 63, quad = lane >> 4,
              ln = lane & 15;
    const int i0 = blockIdx.x * 64;
    const int row = tid >> 2, c = tid & 3;
    const int wofs = row * 32 + ((c + (row >> 1)) & 3) * 8;

    f32x4 acc[4];
#pragma unroll
    for (int ns = 0; ns < 4; ++ns) acc[ns] = (f32x4){0.f, 0.f, 0.f, 0.f};

    const int ar = wave * 16 + ln;
    const int aofs = ar * 32 + ((quad + (ar >> 1)) & 3) * 8;
    int bofs[4];
#pragma unroll
    for (int ns = 0; ns < 4; ++ns) {
        const int br = ns * 16 + ln;
        bofs[ns] = br * 32 + ((quad + (br >> 1)) & 3) * 8;
    }

    for (int kt = 0; kt < 16; ++kt) {
        __syncthreads();
        {
            const float* src = xs + (size_t)(i0 + row) * DIM + kt * 32 + c * 8;
            const float4 f0 = *(const float4*)src, f1 = *(const float4*)(src + 4);
            float v[8] = {f0.x, f0.y, f0.z, f0.w, f1.x, f1.y, f1.z, f1.w};
            u16x8 h8, m8, l8;
            split3(v, h8, m8, l8);
            *(u16x8*)(lAh + wofs) = h8;
            *(u16x8*)(lAm + wofs) = m8;
            *(u16x8*)(lAl + wofs) = l8;
        }
        {
            const float* src = W1 + (size_t)row * DIM + kt * 32 + c * 8;
            const float4 f0 = *(const float4*)src, f1 = *(const float4*)(src + 4);
            float v[8] = {f0.x, f0.y, f0.z, f0.w, f1.x, f1.y, f1.z, f1.w};
            u16x8 h8, m8, l8;
            split3(v, h8, m8, l8);
            *(u16x8*)(lWh + wofs) = h8;
            *(u16x8*)(lWm + wofs) = m8;
            *(u16x8*)(lWl + wofs) = l8;
        }
        __syncthreads();
        const bf16x8 ah = *(const bf16x8*)(lAh + aofs);
        const bf16x8 am = *(const bf16x8*)(lAm + aofs);
        const bf16x8 al = *(const bf16x8*)(lAl + aofs);
#pragma unroll
        for (int ns = 0; ns < 4; ++ns) {
            const bf16x8 bh = *(const bf16x8*)(lWh + bofs[ns]);
            const bf16x8 bm = *(const bf16x8*)(lWm + bofs[ns]);
            const bf16x8 bl = *(const bf16x8*)(lWl + bofs[ns]);
            acc[ns] = __builtin_amdgcn_mfma_f32_16x16x32_bf16(ah, bh, acc[ns], 0, 0, 0);
            acc[ns] = __builtin_amdgcn_mfma_f32_16x16x32_bf16(ah, bm, acc[ns], 0, 0, 0);
            acc[ns] = __builtin_amdgcn_mfma_f32_16x16x32_bf16(am, bh, acc[ns], 0, 0, 0);
            acc[ns] = __builtin_amdgcn_mfma_f32_16x16x32_bf16(am, bm, acc[ns], 0, 0, 0);
            acc[ns] = __builtin_amdgcn_mfma_f32_16x16x32_bf16(ah, bl, acc[ns], 0, 0, 0);
            acc[ns] = __builtin_amdgcn_mfma_f32_16x16x32_bf16(al, bh, acc[ns], 0, 0, 0);
        }
    }
#pragma unroll
    for (int ns = 0; ns < 4; ++ns)
#pragma unroll
        for (int v = 0; v < 4; ++v)
            P[(size_t)(i0 + wave * 16 + quad * 4 + v) * 64 + ns * 16 + ln] = acc[ns][v];
}

// ---------------------------------------------------------------- k_mid  (unchanged R13)
__global__ __launch_bounds__(256) void k_mid(const float* __restrict__ P,
                                             const unsigned long long* __restrict__ nn,
                                             const float* __restrict__ b1,
                                             const float* __restrict__ W2,
                                             const float* __restrict__ b2,
                                             const float* __restrict__ W3,
                                             const float* __restrict__ b3,
                                             const float* __restrict__ D1,
                                             const float* __restrict__ d1,
                                             const float* __restrict__ D2,
                                             const float* __restrict__ d2,
                                             float* __restrict__ out_zs,
                                             float* __restrict__ G2) {
    __shared__ float W2T[64 * 32], W3T[32 * 32], D1T[32 * 32], D2T[32 * 64];
    __shared__ float b2f[32], b3f[32], d1f[32], d2f[64];
    const int tid = threadIdx.x;
    for (int t = tid; t < 2048; t += 256) { int o = t >> 6, k = t & 63; W2T[k * 32 + o] = W2[t]; }
    for (int t = tid; t < 1024; t += 256) { int o = t >> 5, k = t & 31; W3T[k * 32 + o] = W3[t]; }
    for (int t = tid; t < 1024; t += 256) { int o = t >> 5, k = t & 31; D1T[k * 32 + o] = D1[t]; }
    for (int t = tid; t < 2048; t += 256) { int o = t >> 5, k = t & 31; D2T[k * 64 + o] = D2[t]; }
    if (tid < 32) b2f[tid] = b2[tid];
    else if (tid < 64) b3f[tid - 32] = b3[tid - 32];
    else if (tid < 96) d1f[tid - 64] = d1[tid - 64];
    else if (tid < 160) d2f[tid - 96] = d2[tid - 96];
    __syncthreads();

    const int wave = tid >> 6, lane = tid & 63;
    const int wgid = blockIdx.x * 4 + wave;  // 0..4095
    const int o32 = lane & 31;
    const float b1v = b1[lane];
    for (int r = 0; r < 2; ++r) {
        const int row = wgid + r * 4096;
        const unsigned int nnr = (unsigned int)(nn[row] & 0xFFFFFFFFull) & 8191u;
        const float pr = P[(size_t)row * 64 + lane];
        const float p0 = P[(size_t)nnr * 64 + lane];
        const float a1 = p0 + b1v;
        const float u1 = pr - p0;
        const float h1 = fmaxf(a1, 0.f);
        const float th1 = (a1 > 0.f) ? u1 : 0.f;
        float a2 = b2f[o32], u2 = 0.f;
#pragma unroll
        for (int k = 0; k < 64; ++k) {
            const float h = __shfl(h1, k);
            const float t = __shfl(th1, k);
            const float w = W2T[k * 32 + o32];
            a2 = fmaf(h, w, a2);
            u2 = fmaf(t, w, u2);
        }
        const float s = fmaxf(a2, 0.f) + ((a2 > 0.f) ? u2 : 0.f);
        float z = b3f[o32];
#pragma unroll
        for (int k = 0; k < 32; ++k) z = fmaf(__shfl(s, k), W3T[k * 32 + o32], z);
        if (lane < 32) out_zs[(size_t)row * 32 + lane] = z;
        float g1 = d1f[o32];
#pragma unroll
        for (int k = 0; k < 32; ++k) g1 = fmaf(__shfl(z, k), D1T[k * 32 + o32], g1);
        g1 = fmaxf(g1, 0.f);
        float g2 = d2f[lane];
#pragma unroll
        for (int k = 0; k < 32; ++k) g2 = fmaf(__shfl(g1, k), D2T[k * 64 + lane], g2);
        g2 = fmaxf(g2, 0.f);
        G2[(size_t)row * 64 + lane] = g2;
    }
}

// ---------------------------------------------------------------- k_dec  (unchanged)
__global__ __launch_bounds__(256) void k_dec(const float* __restrict__ G2,
                                             const float* __restrict__ D3,
                                             const float* __restrict__ d3,
                                             float* __restrict__ xhat) {
    __shared__ __align__(16) unsigned short lGh[128 * 64], lGl[128 * 64];
    __shared__ __align__(16) unsigned short lDh[128 * 64], lDl[128 * 64];
    const int tid = threadIdx.x, wave = tid >> 6, lane = tid & 63, quad = lane >> 4,
              ln = lane & 15;
    const int i0 = blockIdx.x * 128, nbase = blockIdx.y * 128;
    const int m_off = (wave & 1) * 64, n_off = (wave >> 1) * 64;
#pragma unroll
    for (int r = 0; r < 4; ++r) {
        const int g = r * 256 + tid;
        const int row = g >> 3, cIdx = g & 7, half = cIdx >> 2, cc = cIdx & 3;
        const int wofs = row * 64 + half * 32 + ((cc + (row >> 1)) & 3) * 8;
        {
            const float* src = G2 + (size_t)(i0 + row) * 64 + cIdx * 8;
            const float4 f0 = *(const float4*)src, f1 = *(const float4*)(src + 4);
            float v[8] = {f0.x, f0.y, f0.z, f0.w, f1.x, f1.y, f1.z, f1.w};
            u16x8 h8, l8;
            split2(v, h8, l8);
            *(u16x8*)(lGh + wofs) = h8;
            *(u16x8*)(lGl + wofs) = l8;
        }
        {
            const float* src = D3 + (size_t)(nbase + row) * 64 + cIdx * 8;
            const float4 f0 = *(const float4*)src, f1 = *(const float4*)(src + 4);
            float v[8] = {f0.x, f0.y, f0.z, f0.w, f1.x, f1.y, f1.z, f1.w};
            u16x8 h8, l8;
            split2(v, h8, l8);
            *(u16x8*)(lDh + wofs) = h8;
            *(u16x8*)(lDl + wofs) = l8;
        }
    }
    __syncthreads();
    f32x4 acc[4][4];
#pragma unroll
    for (int a = 0; a < 4; ++a)
#pragma unroll
        for (int c = 0; c < 4; ++c) acc[a][c] = (f32x4){0.f, 0.f, 0.f, 0.f};
#pragma unroll
    for (int kk = 0; kk < 2; ++kk) {
        bf16x8 ah[4], al[4], bh[4], bl[4];
#pragma unroll
        for (int ms = 0; ms < 4; ++ms) {
            const int ar = m_off + ms * 16 + ln;
            const int aofs = ar * 64 + kk * 32 + ((quad + (ar >> 1)) & 3) * 8;
            ah[ms] = *(const bf16x8*)(lGh + aofs);
            al[ms] = *(const bf16x8*)(lGl + aofs);
        }
#pragma unroll
        for (int ns = 0; ns < 4; ++ns) {
            const int br = n_off + ns * 16 + ln;
            const int bofs = br * 64 + kk * 32 + ((quad + (br >> 1)) & 3) * 8;
            bh[ns] = *(const bf16x8*)(lDh + bofs);
            bl[ns] = *(const bf16x8*)(lDl + bofs);
        }
#pragma unroll
        for (int ms = 0; ms < 4; ++ms)
#pragma unroll
            for (int ns = 0; ns < 4; ++ns) {
                acc[ms][ns] = __builtin_amdgcn_mfma_f32_16x16x32_bf16(
                    ah[ms], bh[ns], acc[ms][ns], 0, 0, 0);
                acc[ms][ns] = __builtin_amdgcn_mfma_f32_16x16x32_bf16(
                    ah[ms], bl[ns], acc[ms][ns], 0, 0, 0);
                acc[ms][ns] = __builtin_amdgcn_mfma_f32_16x16x32_bf16(
                    al[ms], bh[ns], acc[ms][ns], 0, 0, 0);
            }
    }
    float d3f[4];
#pragma unroll
    for (int ns = 0; ns < 4; ++ns) d3f[ns] = d3[nbase + n_off + ns * 16 + ln];
#pragma unroll
    for (int ms = 0; ms < 4; ++ms)
#pragma unroll
        for (int ns = 0; ns < 4; ++ns)
#pragma unroll
            for (int v = 0; v < 4; ++v) {
                const int m = m_off + ms * 16 + quad * 4 + v;
                const int n = n_off + ns * 16 + ln;
                xhat[(size_t)(i0 + m) * DIM + nbase + n] = acc[ms][ns][v] + d3f[ns];
            }
}

extern "C" void kernel_launch(void* const* d_in, const int* in_sizes, int n_in,
                              void* d_out, int out_size, void* d_ws, size_t ws_size,
                              hipStream_t stream) {
    const float* xs = (const float*)d_in[0];
    const float* W1 = (const float*)d_in[1];
    const float* b1 = (const float*)d_in[2];
    const float* W2 = (const float*)d_in[3];
    const float* b2 = (const float*)d_in[4];
    const float* W3 = (const float*)d_in[5];
    const float* b3 = (const float*)d_in[6];
    const float* D1 = (const float*)d_in[7];
    const float* d1 = (const float*)d_in[8];
    const float* D2 = (const float*)d_in[9];
    const float* d2 = (const float*)d_in[10];
    const float* D3 = (const float*)d_in[11];
    const float* d3 = (const float*)d_in[12];

    // ws (12.7 MB, proven-safe layout): sq | nn | xs_hi | P | G2
    char* ws = (char*)d_ws;
    float* sq = (float*)(ws);                                     // 32 KB
    unsigned long long* nn = (unsigned long long*)(ws + 32768);   // 64 KB
    unsigned short* xs_hi = (unsigned short*)(ws + 131072);       // 8 MB
    float* P = (float*)(ws + 8519680);                            // 2 MB
    float* G2 = (float*)(ws + 10616832);                          // 2 MB

    float* xhat = (float*)d_out;
    float* zs = (float*)d_out + (size_t)NROWS * DIM;
    // rowtab scratch (u32, 8.7 MB) lives in d_out's dead space
    unsigned int* rowtab = (unsigned int*)d_out;

    hipLaunchKernelGGL(k_prep, dim3(2048), dim3(256), 0, stream, xs, xs_hi, sq);
    hipLaunchKernelGGL(k_nn, dim3(1088), dim3(256), 0, stream, xs_hi, sq, rowtab);
    hipLaunchKernelGGL(k_refine, dim3(2048), dim3(256), 0, stream, rowtab, xs, sq, nn);
    hipLaunchKernelGGL(k_p, dim3(128), dim3(256), 0, stream, xs, W1, P);
    hipLaunchKernelGGL(k_mid, dim3(1024), dim3(256), 0, stream, P, nn, b1, W2, b2, W3,
                       b3, D1, d1, D2, d2, zs, G2);
    hipLaunchKernelGGL(k_dec, dim3(64, 4), dim3(256), 0, stream, G2, D3, d3, xhat);
}

// Round 15
// 256.430 us; speedup vs baseline: 1.1891x; 1.1891x over previous
//
#include <hip/hip_runtime.h>
#include <hip/hip_bf16.h>

#define NROWS 8192
#define DIM 512
#define NSLOT 130  // per-row top-2 slots: 66 row-side + 64 col-side
#define KMASK 0xFFFFE000u  // top-19 key bits; low 13 = index

typedef __attribute__((ext_vector_type(8))) short bf16x8;
typedef __attribute__((ext_vector_type(4))) float f32x4;
typedef __attribute__((ext_vector_type(8))) unsigned short u16x8;

__device__ __forceinline__ float bf2f(unsigned short u) {
    return __uint_as_float(((unsigned int)u) << 16);
}
__device__ __forceinline__ unsigned short f2bf(float f) {
    unsigned int b = __float_as_uint(f);
    return (unsigned short)((b + 0x7FFFu + ((b >> 16) & 1u)) >> 16);
}
// monotone float->uint key: a<b <=> fkey(a)<fkey(b)
__device__ __forceinline__ unsigned int fkey(float f) {
    unsigned int b = __float_as_uint(f);
    return (b & 0x80000000u) ? ~b : (b | 0x80000000u);
}
__device__ __forceinline__ float unfkey(unsigned int u) {
    unsigned int b = (u & 0x80000000u) ? (u ^ 0x80000000u) : ~u;
    return __uint_as_float(b);
}
__device__ __forceinline__ unsigned int minu(unsigned int a, unsigned int b) {
    return a < b ? a : b;
}
__device__ __forceinline__ unsigned long long min64(unsigned long long a,
                                                    unsigned long long b) {
    return a < b ? a : b;
}

// helper: 3-way bf16 split
__device__ __forceinline__ void split3(const float* v, u16x8& h8, u16x8& m8, u16x8& l8) {
#pragma unroll
    for (int j = 0; j < 8; ++j) {
        const float x = v[j];
        const unsigned short h = f2bf(x);
        const float r1 = x - bf2f(h);
        const unsigned short m = f2bf(r1);
        const float r2 = r1 - bf2f(m);
        h8[j] = h; m8[j] = m; l8[j] = f2bf(r2);
    }
}
// helper: 2-way split
__device__ __forceinline__ void split2(const float* v, u16x8& h8, u16x8& l8) {
#pragma unroll
    for (int j = 0; j < 8; ++j) {
        const float x = v[j];
        const unsigned short h = f2bf(x);
        h8[j] = h; l8[j] = f2bf(x - bf2f(h));
    }
}

// ---------------------------------------------------------------- k_prep_p
// Merged: blocks 0..2047 = prep (bf16-hi plane + sq); blocks 2048..2175 =
// P = xs @ W1^T via 3-way-split bf16 MFMA (R13's k_p body, bit-identical).
__global__ __launch_bounds__(256) void k_prep_p(const float* __restrict__ xs,
                                                unsigned short* __restrict__ hi,
                                                float* __restrict__ sq,
                                                const float* __restrict__ W1,
                                                float* __restrict__ P) {
    __shared__ __align__(16) unsigned short lAh[64 * 32], lAm[64 * 32], lAl[64 * 32];
    __shared__ __align__(16) unsigned short lWh[64 * 32], lWm[64 * 32], lWl[64 * 32];
    const int tid = threadIdx.x;
    if (blockIdx.x < 2048) {
        const int wave = tid >> 6, lane = tid & 63;
        const int row = blockIdx.x * 4 + wave;
        const float4* xr = (const float4*)(xs + (size_t)row * DIM);
        const float4 a = xr[2 * lane], b = xr[2 * lane + 1];
        float v[8] = {a.x, a.y, a.z, a.w, b.x, b.y, b.z, b.w};
        u16x8 h;
        float s = 0.f;
#pragma unroll
        for (int i = 0; i < 8; ++i) {
            h[i] = f2bf(v[i]);
            s = fmaf(v[i], v[i], s);
        }
        *(u16x8*)(hi + (size_t)row * DIM + lane * 8) = h;
#pragma unroll
        for (int d = 32; d; d >>= 1) s += __shfl_xor(s, d);
        if (lane == 0) sq[row] = s;
        return;
    }
    // ---- k_p body ----
    const int wave = tid >> 6, lane = tid & 63, quad = lane >> 4, ln = lane & 15;
    const int i0 = (blockIdx.x - 2048) * 64;
    const int row = tid >> 2, c = tid & 3;
    const int wofs = row * 32 + ((c + (row >> 1)) & 3) * 8;

    f32x4 acc[4];
#pragma unroll
    for (int ns = 0; ns < 4; ++ns) acc[ns] = (f32x4){0.f, 0.f, 0.f, 0.f};

    const int ar = wave * 16 + ln;
    const int aofs = ar * 32 + ((quad + (ar >> 1)) & 3) * 8;
    int bofs[4];
#pragma unroll
    for (int ns = 0; ns < 4; ++ns) {
        const int br = ns * 16 + ln;
        bofs[ns] = br * 32 + ((quad + (br >> 1)) & 3) * 8;
    }

    for (int kt = 0; kt < 16; ++kt) {
        __syncthreads();
        {
            const float* src = xs + (size_t)(i0 + row) * DIM + kt * 32 + c * 8;
            const float4 f0 = *(const float4*)src, f1 = *(const float4*)(src + 4);
            float v[8] = {f0.x, f0.y, f0.z, f0.w, f1.x, f1.y, f1.z, f1.w};
            u16x8 h8, m8, l8;
            split3(v, h8, m8, l8);
            *(u16x8*)(lAh + wofs) = h8;
            *(u16x8*)(lAm + wofs) = m8;
            *(u16x8*)(lAl + wofs) = l8;
        }
        {
            const float* src = W1 + (size_t)row * DIM + kt * 32 + c * 8;
            const float4 f0 = *(const float4*)src, f1 = *(const float4*)(src + 4);
            float v[8] = {f0.x, f0.y, f0.z, f0.w, f1.x, f1.y, f1.z, f1.w};
            u16x8 h8, m8, l8;
            split3(v, h8, m8, l8);
            *(u16x8*)(lWh + wofs) = h8;
            *(u16x8*)(lWm + wofs) = m8;
            *(u16x8*)(lWl + wofs) = l8;
        }
        __syncthreads();
        const bf16x8 ah = *(const bf16x8*)(lAh + aofs);
        const bf16x8 am = *(const bf16x8*)(lAm + aofs);
        const bf16x8 al = *(const bf16x8*)(lAl + aofs);
#pragma unroll
        for (int ns = 0; ns < 4; ++ns) {
            const bf16x8 bh = *(const bf16x8*)(lWh + bofs[ns]);
            const bf16x8 bm = *(const bf16x8*)(lWm + bofs[ns]);
            const bf16x8 bl = *(const bf16x8*)(lWl + bofs[ns]);
            acc[ns] = __builtin_amdgcn_mfma_f32_16x16x32_bf16(ah, bh, acc[ns], 0, 0, 0);
            acc[ns] = __builtin_amdgcn_mfma_f32_16x16x32_bf16(ah, bm, acc[ns], 0, 0, 0);
            acc[ns] = __builtin_amdgcn_mfma_f32_16x16x32_bf16(am, bh, acc[ns], 0, 0, 0);
            acc[ns] = __builtin_amdgcn_mfma_f32_16x16x32_bf16(am, bm, acc[ns], 0, 0, 0);
            acc[ns] = __builtin_amdgcn_mfma_f32_16x16x32_bf16(ah, bl, acc[ns], 0, 0, 0);
            acc[ns] = __builtin_amdgcn_mfma_f32_16x16x32_bf16(al, bh, acc[ns], 0, 0, 0);
        }
    }
#pragma unroll
    for (int ns = 0; ns < 4; ++ns)
#pragma unroll
        for (int v = 0; v < 4; ++v)
            P[(size_t)(i0 + wave * 16 + quad * 4 + v) * 64 + ns * 16 + ln] = acc[ns][v];
}

// ---------------------------------------------------------------- k_nn  (R13 exact)
__global__ __launch_bounds__(256) void k_nn(const unsigned short* __restrict__ xh,
                                            const float* __restrict__ sq,
                                            unsigned int* __restrict__ rowtab) {
    __shared__ __align__(16) unsigned short lA[2 * 128 * 32];
    __shared__ __align__(16) unsigned short lB[2 * 128 * 32];
    const int tid = threadIdx.x;
    const int wave = tid >> 6, lane = tid & 63, quad = lane >> 4, ln = lane & 15;
    const int b = blockIdx.x;
    const int xcd = b & 7, w = b >> 3;
    const int s = w >> 3, bil = w & 7;
    const int bi = xcd * 8 + bil;
    const int bj = (bi + s) & 63;
    const int i0 = bi * 128, j0 = bj * 128;
    const int m_off = (wave & 1) * 64, n_off = (wave >> 1) * 64;

    const int rl = lane >> 2;
    const int cc = ((lane & 3) - (rl >> 1)) & 3;
    unsigned short* lbase = ((wave < 2) ? lA : lB) + (wave & 1) * 2048;
    const int trow = ((wave < 2) ? i0 : j0) + (wave & 1) * 64;
    const unsigned short* gp = xh + (size_t)(trow + rl) * DIM + cc * 8;

    int aoff[4], boff[4];
#pragma unroll
    for (int ms = 0; ms < 4; ++ms) {
        const int r = m_off + ms * 16 + ln;
        aoff[ms] = r * 32 + ((quad + (r >> 1)) & 3) * 8;
    }
#pragma unroll
    for (int ns = 0; ns < 4; ++ns) {
        const int r = n_off + ns * 16 + ln;
        boff[ns] = r * 32 + ((quad + (r >> 1)) & 3) * 8;
    }

    f32x4 acc[4][4];
#pragma unroll
    for (int a = 0; a < 4; ++a)
#pragma unroll
        for (int c = 0; c < 4; ++c) acc[a][c] = (f32x4){0.f, 0.f, 0.f, 0.f};

#pragma unroll
    for (int st = 0; st < 4; ++st)
        __builtin_amdgcn_global_load_lds(
            (const __attribute__((address_space(1))) void*)(gp + (size_t)(st * 16) * DIM),
            (__attribute__((address_space(3))) void*)(lbase + st * 512), 16, 0, 0);

    for (int kt = 0; kt < 16; ++kt) {
        __syncthreads();
        const int cur = (kt & 1) * 4096;
        if (kt < 15) {
            const int nxt = ((kt + 1) & 1) * 4096;
            const unsigned short* g = gp + (kt + 1) * 32;
#pragma unroll
            for (int st = 0; st < 4; ++st)
                __builtin_amdgcn_global_load_lds(
                    (const __attribute__((address_space(1))) void*)(g + (size_t)(st * 16) * DIM),
                    (__attribute__((address_space(3))) void*)(lbase + nxt + st * 512),
                    16, 0, 0);
        }
        bf16x8 ah[4], bh[4];
#pragma unroll
        for (int ms = 0; ms < 4; ++ms)
            ah[ms] = *(const bf16x8*)(lA + cur + aoff[ms]);
#pragma unroll
        for (int ns = 0; ns < 4; ++ns)
            bh[ns] = *(const bf16x8*)(lB + cur + boff[ns]);
#pragma unroll
        for (int ms = 0; ms < 4; ++ms)
#pragma unroll
            for (int ns = 0; ns < 4; ++ns)
                acc[ms][ns] = __builtin_amdgcn_mfma_f32_16x16x32_bf16(
                    ah[ms], bh[ns], acc[ms][ns], 0, 0, 0);
    }

    const bool diag = (i0 == j0);
    float sqj[4];
#pragma unroll
    for (int ns = 0; ns < 4; ++ns) sqj[ns] = sq[j0 + n_off + ns * 16 + ln];
    float sqi[4][4];
#pragma unroll
    for (int ms = 0; ms < 4; ++ms)
#pragma unroll
        for (int v = 0; v < 4; ++v)
            sqi[ms][v] = sq[i0 + m_off + ms * 16 + quad * 4 + v];

#pragma unroll
    for (int ms = 0; ms < 4; ++ms)
#pragma unroll
        for (int v = 0; v < 4; ++v) {
            const int gi = i0 + m_off + ms * 16 + quad * 4 + v;
            unsigned int pk[4];
#pragma unroll
            for (int ns = 0; ns < 4; ++ns) {
                const int gj = j0 + n_off + ns * 16 + ln;
                float d2 = fmaf(-2.f, acc[ms][ns][v], sqj[ns]);
                if (diag && gj == gi) d2 = __builtin_inff();
                pk[ns] = (fkey(d2) & KMASK) | (unsigned int)gj;
            }
            unsigned int m1 = minu(minu(pk[0], pk[1]), minu(pk[2], pk[3]));
#pragma unroll
            for (int d = 1; d < 16; d <<= 1) m1 = minu(m1, __shfl_xor(m1, d));
            unsigned int m2 = 0xFFFFFFFFu;
#pragma unroll
            for (int ns = 0; ns < 4; ++ns)
                m2 = minu(m2, pk[ns] == m1 ? 0xFFFFFFFFu : pk[ns]);
#pragma unroll
            for (int d = 1; d < 16; d <<= 1) m2 = minu(m2, __shfl_xor(m2, d));
            if (ln == 0) {
                const size_t base = ((size_t)gi * NSLOT + (s * 2 + (wave >> 1))) * 2;
                rowtab[base] = m1;
                rowtab[base + 1] = m2;
            }
        }
    if (s > 0) {
#pragma unroll
        for (int ns = 0; ns < 4; ++ns) {
            const int gj = j0 + n_off + ns * 16 + ln;
            unsigned int pk[16];
#pragma unroll
            for (int ms = 0; ms < 4; ++ms)
#pragma unroll
                for (int v = 0; v < 4; ++v) {
                    const int gi = i0 + m_off + ms * 16 + quad * 4 + v;
                    const float d2 = fmaf(-2.f, acc[ms][ns][v], sqi[ms][v]);
                    pk[ms * 4 + v] = (fkey(d2) & KMASK) | (unsigned int)gi;
                }
            unsigned int m1 = pk[0];
#pragma unroll
            for (int t = 1; t < 16; ++t) m1 = minu(m1, pk[t]);
            m1 = minu(m1, __shfl_xor(m1, 16));
            m1 = minu(m1, __shfl_xor(m1, 32));
            unsigned int m2 = 0xFFFFFFFFu;
#pragma unroll
            for (int t = 0; t < 16; ++t)
                m2 = minu(m2, pk[t] == m1 ? 0xFFFFFFFFu : pk[t]);
            m2 = minu(m2, __shfl_xor(m2, 16));
            m2 = minu(m2, __shfl_xor(m2, 32));
            if (quad == 0) {
                const size_t base =
                    ((size_t)gj * NSLOT + (66 + (s - 1) * 2 + (wave & 1))) * 2;
                rowtab[base] = m1;
                rowtab[base + 1] = m2;
            }
        }
    }
}

// ---------------------------------------------------------------- k_refine  (R13 exact)
__global__ __launch_bounds__(256) void k_refine(const unsigned int* __restrict__ rowtab,
                                                const float* __restrict__ xs,
                                                const float* __restrict__ sq,
                                                unsigned long long* __restrict__ nn) {
    __shared__ unsigned int clist[4][64];
    __shared__ int ccnt[4];
    const int wave = threadIdx.x >> 6, lane = threadIdx.x & 63;
    const int row = blockIdx.x * 4 + wave;
    if (lane == 0) ccnt[wave] = 0;
    __syncthreads();

    unsigned int vals[5];
    int nv = 0;
    unsigned int best = 0xFFFFFFFFu;
    for (int i = lane; i < NSLOT * 2; i += 64) {
        const unsigned int v = rowtab[(size_t)row * NSLOT * 2 + i];
        vals[nv++] = v;
        best = minu(best, v);
    }
#pragma unroll
    for (int d = 1; d < 64; d <<= 1) best = minu(best, __shfl_xor(best, d));

    const float dmin = unfkey(best & KMASK);
    const unsigned int tkey = fkey(dmin + 4.0f);
    for (int k = 0; k < nv; ++k)
        if ((vals[k] & KMASK) < tkey) {
            const int p = atomicAdd(&ccnt[wave], 1);
            if (p < 64) clist[wave][p] = vals[k] & 8191u;
        }
    __syncthreads();
    int cnt = ccnt[wave];
    cnt = cnt > 64 ? 64 : cnt;

    const float4* xi = (const float4*)(xs + (size_t)row * DIM);
    const float4 x0 = xi[2 * lane], x1 = xi[2 * lane + 1];
    const float sqi = sq[row];
    unsigned long long bestf = ~0ull;
    for (int c = 0; c < cnt; ++c) {
        const unsigned int j = clist[wave][c];
        const float4* xj = (const float4*)(xs + (size_t)j * DIM);
        const float4 y0 = xj[2 * lane], y1 = xj[2 * lane + 1];
        float dot = 0.f;
        dot = fmaf(x0.x, y0.x, dot); dot = fmaf(x0.y, y0.y, dot);
        dot = fmaf(x0.z, y0.z, dot); dot = fmaf(x0.w, y0.w, dot);
        dot = fmaf(x1.x, y1.x, dot); dot = fmaf(x1.y, y1.y, dot);
        dot = fmaf(x1.z, y1.z, dot); dot = fmaf(x1.w, y1.w, dot);
#pragma unroll
        for (int d = 1; d < 64; d <<= 1) dot += __shfl_xor(dot, d);
        const float d2 = sqi + sq[j] - 2.f * dot;
        const unsigned long long pk = (((unsigned long long)fkey(d2)) << 32) | j;
        bestf = min64(bestf, pk);
    }
    if (lane == 0) nn[row] = bestf;
}

// ---------------------------------------------------------------- k_mid  (R13 exact)
__global__ __launch_bounds__(256) void k_mid(const float* __restrict__ P,
                                             const unsigned long long* __restrict__ nn,
                                             const float* __restrict__ b1,
                                             const float* __restrict__ W2,
                                             const float* __restrict__ b2,
                                             const float* __restrict__ W3,
                                             const float* __restrict__ b3,
                                             const float* __restrict__ D1,
                                             const float* __restrict__ d1,
                                             const float* __restrict__ D2,
                                             const float* __restrict__ d2,
                                             float* __restrict__ out_zs,
                                             float* __restrict__ G2) {
    __shared__ float W2T[64 * 32], W3T[32 * 32], D1T[32 * 32], D2T[32 * 64];
    __shared__ float b2f[32], b3f[32], d1f[32], d2f[64];
    const int tid = threadIdx.x;
    for (int t = tid; t < 2048; t += 256) { int o = t >> 6, k = t & 63; W2T[k * 32 + o] = W2[t]; }
    for (int t = tid; t < 1024; t += 256) { int o = t >> 5, k = t & 31; W3T[k * 32 + o] = W3[t]; }
    for (int t = tid; t < 1024; t += 256) { int o = t >> 5, k = t & 31; D1T[k * 32 + o] = D1[t]; }
    for (int t = tid; t < 2048; t += 256) { int o = t >> 5, k = t & 31; D2T[k * 64 + o] = D2[t]; }
    if (tid < 32) b2f[tid] = b2[tid];
    else if (tid < 64) b3f[tid - 32] = b3[tid - 32];
    else if (tid < 96) d1f[tid - 64] = d1[tid - 64];
    else if (tid < 160) d2f[tid - 96] = d2[tid - 96];
    __syncthreads();

    const int wave = tid >> 6, lane = tid & 63;
    const int wgid = blockIdx.x * 4 + wave;  // 0..4095
    const int o32 = lane & 31;
    const float b1v = b1[lane];
    for (int r = 0; r < 2; ++r) {
        const int row = wgid + r * 4096;
        const unsigned int nnr = (unsigned int)(nn[row] & 0xFFFFFFFFull) & 8191u;
        const float pr = P[(size_t)row * 64 + lane];
        const float p0 = P[(size_t)nnr * 64 + lane];
        const float a1 = p0 + b1v;
        const float u1 = pr - p0;
        const float h1 = fmaxf(a1, 0.f);
        const float th1 = (a1 > 0.f) ? u1 : 0.f;
        float a2 = b2f[o32], u2 = 0.f;
#pragma unroll
        for (int k = 0; k < 64; ++k) {
            const float h = __shfl(h1, k);
            const float t = __shfl(th1, k);
            const float w = W2T[k * 32 + o32];
            a2 = fmaf(h, w, a2);
            u2 = fmaf(t, w, u2);
        }
        const float s = fmaxf(a2, 0.f) + ((a2 > 0.f) ? u2 : 0.f);
        float z = b3f[o32];
#pragma unroll
        for (int k = 0; k < 32; ++k) z = fmaf(__shfl(s, k), W3T[k * 32 + o32], z);
        if (lane < 32) out_zs[(size_t)row * 32 + lane] = z;
        float g1 = d1f[o32];
#pragma unroll
        for (int k = 0; k < 32; ++k) g1 = fmaf(__shfl(z, k), D1T[k * 32 + o32], g1);
        g1 = fmaxf(g1, 0.f);
        float g2 = d2f[lane];
#pragma unroll
        for (int k = 0; k < 32; ++k) g2 = fmaf(__shfl(g1, k), D2T[k * 64 + lane], g2);
        g2 = fmaxf(g2, 0.f);
        G2[(size_t)row * 64 + lane] = g2;
    }
}

// ---------------------------------------------------------------- k_dec  (R13 exact)
__global__ __launch_bounds__(256) void k_dec(const float* __restrict__ G2,
                                             const float* __restrict__ D3,
                                             const float* __restrict__ d3,
                                             float* __restrict__ xhat) {
    __shared__ __align__(16) unsigned short lGh[128 * 64], lGl[128 * 64];
    __shared__ __align__(16) unsigned short lDh[128 * 64], lDl[128 * 64];
    const int tid = threadIdx.x, wave = tid >> 6, lane = tid & 63, quad = lane >> 4,
              ln = lane & 15;
    const int i0 = blockIdx.x * 128, nbase = blockIdx.y * 128;
    const int m_off = (wave & 1) * 64, n_off = (wave >> 1) * 64;
#pragma unroll
    for (int r = 0; r < 4; ++r) {
        const int g = r * 256 + tid;
        const int row = g >> 3, cIdx = g & 7, half = cIdx >> 2, cc = cIdx & 3;
        const int wofs = row * 64 + half * 32 + ((cc + (row >> 1)) & 3) * 8;
        {
            const float* src = G2 + (size_t)(i0 + row) * 64 + cIdx * 8;
            const float4 f0 = *(const float4*)src, f1 = *(const float4*)(src + 4);
            float v[8] = {f0.x, f0.y, f0.z, f0.w, f1.x, f1.y, f1.z, f1.w};
            u16x8 h8, l8;
            split2(v, h8, l8);
            *(u16x8*)(lGh + wofs) = h8;
            *(u16x8*)(lGl + wofs) = l8;
        }
        {
            const float* src = D3 + (size_t)(nbase + row) * 64 + cIdx * 8;
            const float4 f0 = *(const float4*)src, f1 = *(const float4*)(src + 4);
            float v[8] = {f0.x, f0.y, f0.z, f0.w, f1.x, f1.y, f1.z, f1.w};
            u16x8 h8, l8;
            split2(v, h8, l8);
            *(u16x8*)(lDh + wofs) = h8;
            *(u16x8*)(lDl + wofs) = l8;
        }
    }
    __syncthreads();
    f32x4 acc[4][4];
#pragma unroll
    for (int a = 0; a < 4; ++a)
#pragma unroll
        for (int c = 0; c < 4; ++c) acc[a][c] = (f32x4){0.f, 0.f, 0.f, 0.f};
#pragma unroll
    for (int kk = 0; kk < 2; ++kk) {
        bf16x8 ah[4], al[4], bh[4], bl[4];
#pragma unroll
        for (int ms = 0; ms < 4; ++ms) {
            const int ar = m_off + ms * 16 + ln;
            const int aofs = ar * 64 + kk * 32 + ((quad + (ar >> 1)) & 3) * 8;
            ah[ms] = *(const bf16x8*)(lGh + aofs);
            al[ms] = *(const bf16x8*)(lGl + aofs);
        }
#pragma unroll
        for (int ns = 0; ns < 4; ++ns) {
            const int br = n_off + ns * 16 + ln;
            const int bofs = br * 64 + kk * 32 + ((quad + (br >> 1)) & 3) * 8;
            bh[ns] = *(const bf16x8*)(lDh + bofs);
            bl[ns] = *(const bf16x8*)(lDl + bofs);
        }
#pragma unroll
        for (int ms = 0; ms < 4; ++ms)
#pragma unroll
            for (int ns = 0; ns < 4; ++ns) {
                acc[ms][ns] = __builtin_amdgcn_mfma_f32_16x16x32_bf16(
                    ah[ms], bh[ns], acc[ms][ns], 0, 0, 0);
                acc[ms][ns] = __builtin_amdgcn_mfma_f32_16x16x32_bf16(
                    ah[ms], bl[ns], acc[ms][ns], 0, 0, 0);
                acc[ms][ns] = __builtin_amdgcn_mfma_f32_16x16x32_bf16(
                    al[ms], bh[ns], acc[ms][ns], 0, 0, 0);
            }
    }
    float d3f[4];
#pragma unroll
    for (int ns = 0; ns < 4; ++ns) d3f[ns] = d3[nbase + n_off + ns * 16 + ln];
#pragma unroll
    for (int ms = 0; ms < 4; ++ms)
#pragma unroll
        for (int ns = 0; ns < 4; ++ns)
#pragma unroll
            for (int v = 0; v < 4; ++v) {
                const int m = m_off + ms * 16 + quad * 4 + v;
                const int n = n_off + ns * 16 + ln;
                xhat[(size_t)(i0 + m) * DIM + nbase + n] = acc[ms][ns][v] + d3f[ns];
            }
}

extern "C" void kernel_launch(void* const* d_in, const int* in_sizes, int n_in,
                              void* d_out, int out_size, void* d_ws, size_t ws_size,
                              hipStream_t stream) {
    const float* xs = (const float*)d_in[0];
    const float* W1 = (const float*)d_in[1];
    const float* b1 = (const float*)d_in[2];
    const float* W2 = (const float*)d_in[3];
    const float* b2 = (const float*)d_in[4];
    const float* W3 = (const float*)d_in[5];
    const float* b3 = (const float*)d_in[6];
    const float* D1 = (const float*)d_in[7];
    const float* d1 = (const float*)d_in[8];
    const float* D2 = (const float*)d_in[9];
    const float* d2 = (const float*)d_in[10];
    const float* D3 = (const float*)d_in[11];
    const float* d3 = (const float*)d_in[12];

    // ws (12.7 MB, proven-safe layout): sq | nn | xs_hi | P | G2
    char* ws = (char*)d_ws;
    float* sq = (float*)(ws);                                     // 32 KB
    unsigned long long* nn = (unsigned long long*)(ws + 32768);   // 64 KB
    unsigned short* xs_hi = (unsigned short*)(ws + 131072);       // 8 MB
    float* P = (float*)(ws + 8519680);                            // 2 MB
    float* G2 = (float*)(ws + 10616832);                          // 2 MB

    float* xhat = (float*)d_out;
    float* zs = (float*)d_out + (size_t)NROWS * DIM;
    // rowtab scratch (u32, 8.5 MB) lives in d_out's dead space
    unsigned int* rowtab = (unsigned int*)d_out;

    hipLaunchKernelGGL(k_prep_p, dim3(2176), dim3(256), 0, stream, xs, xs_hi, sq, W1, P);
    hipLaunchKernelGGL(k_nn, dim3(2112), dim3(256), 0, stream, xs_hi, sq, rowtab);
    hipLaunchKernelGGL(k_refine, dim3(2048), dim3(256), 0, stream, rowtab, xs, sq, nn);
    hipLaunchKernelGGL(k_mid, dim3(1024), dim3(256), 0, stream, P, nn, b1, W2, b2, W3,
                       b3, D1, d1, D2, d2, zs, G2);
    hipLaunchKernelGGL(k_dec, dim3(64, 4), dim3(256), 0, stream, G2, D3, d3, xhat);
}

// Round 16
// 243.979 us; speedup vs baseline: 1.2498x; 1.0510x over previous
//
#include <hip/hip_runtime.h>
#include <hip/hip_bf16.h>

#define NROWS 8192
#define DIM 512
#define NSLOT 130  // per-row top-2 slots: 66 row-side + 64 col-side
#define KMASK 0xFFFFE000u  // top-19 key bits; low 13 = index

typedef __attribute__((ext_vector_type(8))) short bf16x8;
typedef __attribute__((ext_vector_type(4))) float f32x4;
typedef __attribute__((ext_vector_type(8))) unsigned short u16x8;

__device__ __forceinline__ float bf2f(unsigned short u) {
    return __uint_as_float(((unsigned int)u) << 16);
}
__device__ __forceinline__ unsigned short f2bf(float f) {
    unsigned int b = __float_as_uint(f);
    return (unsigned short)((b + 0x7FFFu + ((b >> 16) & 1u)) >> 16);
}
// monotone float->uint key (general form; use pkey for provably-positive vals)
__device__ __forceinline__ unsigned int fkey(float f) {
    unsigned int b = __float_as_uint(f);
    return (b & 0x80000000u) ? ~b : (b | 0x80000000u);
}
// positive-only key: identical to fkey for f >= 0 (single OR)
__device__ __forceinline__ unsigned int pkey(float f) {
    return __float_as_uint(f) | 0x80000000u;
}
__device__ __forceinline__ float unfkey(unsigned int u) {
    unsigned int b = (u & 0x80000000u) ? (u ^ 0x80000000u) : ~u;
    return __uint_as_float(b);
}
__device__ __forceinline__ unsigned int minu(unsigned int a, unsigned int b) {
    return a < b ? a : b;
}
__device__ __forceinline__ unsigned long long min64(unsigned long long a,
                                                    unsigned long long b) {
    return a < b ? a : b;
}

// helper: 3-way bf16 split
__device__ __forceinline__ void split3(const float* v, u16x8& h8, u16x8& m8, u16x8& l8) {
#pragma unroll
    for (int j = 0; j < 8; ++j) {
        const float x = v[j];
        const unsigned short h = f2bf(x);
        const float r1 = x - bf2f(h);
        const unsigned short m = f2bf(r1);
        const float r2 = r1 - bf2f(m);
        h8[j] = h; m8[j] = m; l8[j] = f2bf(r2);
    }
}
// helper: 2-way split
__device__ __forceinline__ void split2(const float* v, u16x8& h8, u16x8& l8) {
#pragma unroll
    for (int j = 0; j < 8; ++j) {
        const float x = v[j];
        const unsigned short h = f2bf(x);
        h8[j] = h; l8[j] = f2bf(x - bf2f(h));
    }
}

// ---------------------------------------------------------------- k_prep_p
// Merged: blocks 0..2047 = prep (bf16-hi plane + sq); blocks 2048..2175 =
// P = xs @ W1^T via 3-way-split bf16 MFMA.
__global__ __launch_bounds__(256) void k_prep_p(const float* __restrict__ xs,
                                                unsigned short* __restrict__ hi,
                                                float* __restrict__ sq,
                                                const float* __restrict__ W1,
                                                float* __restrict__ P) {
    __shared__ __align__(16) unsigned short lAh[64 * 32], lAm[64 * 32], lAl[64 * 32];
    __shared__ __align__(16) unsigned short lWh[64 * 32], lWm[64 * 32], lWl[64 * 32];
    const int tid = threadIdx.x;
    if (blockIdx.x < 2048) {
        const int wave = tid >> 6, lane = tid & 63;
        const int row = blockIdx.x * 4 + wave;
        const float4* xr = (const float4*)(xs + (size_t)row * DIM);
        const float4 a = xr[2 * lane], b = xr[2 * lane + 1];
        float v[8] = {a.x, a.y, a.z, a.w, b.x, b.y, b.z, b.w};
        u16x8 h;
        float s = 0.f;
#pragma unroll
        for (int i = 0; i < 8; ++i) {
            h[i] = f2bf(v[i]);
            s = fmaf(v[i], v[i], s);
        }
        *(u16x8*)(hi + (size_t)row * DIM + lane * 8) = h;
#pragma unroll
        for (int d = 32; d; d >>= 1) s += __shfl_xor(s, d);
        if (lane == 0) sq[row] = s;
        return;
    }
    // ---- k_p body ----
    const int wave = tid >> 6, lane = tid & 63, quad = lane >> 4, ln = lane & 15;
    const int i0 = (blockIdx.x - 2048) * 64;
    const int row = tid >> 2, c = tid & 3;
    const int wofs = row * 32 + ((c + (row >> 1)) & 3) * 8;

    f32x4 acc[4];
#pragma unroll
    for (int ns = 0; ns < 4; ++ns) acc[ns] = (f32x4){0.f, 0.f, 0.f, 0.f};

    const int ar = wave * 16 + ln;
    const int aofs = ar * 32 + ((quad + (ar >> 1)) & 3) * 8;
    int bofs[4];
#pragma unroll
    for (int ns = 0; ns < 4; ++ns) {
        const int br = ns * 16 + ln;
        bofs[ns] = br * 32 + ((quad + (br >> 1)) & 3) * 8;
    }

    for (int kt = 0; kt < 16; ++kt) {
        __syncthreads();
        {
            const float* src = xs + (size_t)(i0 + row) * DIM + kt * 32 + c * 8;
            const float4 f0 = *(const float4*)src, f1 = *(const float4*)(src + 4);
            float v[8] = {f0.x, f0.y, f0.z, f0.w, f1.x, f1.y, f1.z, f1.w};
            u16x8 h8, m8, l8;
            split3(v, h8, m8, l8);
            *(u16x8*)(lAh + wofs) = h8;
            *(u16x8*)(lAm + wofs) = m8;
            *(u16x8*)(lAl + wofs) = l8;
        }
        {
            const float* src = W1 + (size_t)row * DIM + kt * 32 + c * 8;
            const float4 f0 = *(const float4*)src, f1 = *(const float4*)(src + 4);
            float v[8] = {f0.x, f0.y, f0.z, f0.w, f1.x, f1.y, f1.z, f1.w};
            u16x8 h8, m8, l8;
            split3(v, h8, m8, l8);
            *(u16x8*)(lWh + wofs) = h8;
            *(u16x8*)(lWm + wofs) = m8;
            *(u16x8*)(lWl + wofs) = l8;
        }
        __syncthreads();
        const bf16x8 ah = *(const bf16x8*)(lAh + aofs);
        const bf16x8 am = *(const bf16x8*)(lAm + aofs);
        const bf16x8 al = *(const bf16x8*)(lAl + aofs);
#pragma unroll
        for (int ns = 0; ns < 4; ++ns) {
            const bf16x8 bh = *(const bf16x8*)(lWh + bofs[ns]);
            const bf16x8 bm = *(const bf16x8*)(lWm + bofs[ns]);
            const bf16x8 bl = *(const bf16x8*)(lWl + bofs[ns]);
            acc[ns] = __builtin_amdgcn_mfma_f32_16x16x32_bf16(ah, bh, acc[ns], 0, 0, 0);
            acc[ns] = __builtin_amdgcn_mfma_f32_16x16x32_bf16(ah, bm, acc[ns], 0, 0, 0);
            acc[ns] = __builtin_amdgcn_mfma_f32_16x16x32_bf16(am, bh, acc[ns], 0, 0, 0);
            acc[ns] = __builtin_amdgcn_mfma_f32_16x16x32_bf16(am, bm, acc[ns], 0, 0, 0);
            acc[ns] = __builtin_amdgcn_mfma_f32_16x16x32_bf16(ah, bl, acc[ns], 0, 0, 0);
            acc[ns] = __builtin_amdgcn_mfma_f32_16x16x32_bf16(al, bh, acc[ns], 0, 0, 0);
        }
    }
#pragma unroll
    for (int ns = 0; ns < 4; ++ns)
#pragma unroll
        for (int v = 0; v < 4; ++v)
            P[(size_t)(i0 + wave * 16 + quad * 4 + v) * 64 + ns * 16 + ln] = acc[ns][v];
}

// ---------------------------------------------------------------- k_nn
// R13 structure; kt loop fully unrolled (imm LDS offsets, per-stripe DMA base
// pointers) and positive-only 1-op key packing in the epilogue.
__global__ __launch_bounds__(256) void k_nn(const unsigned short* __restrict__ xh,
                                            const float* __restrict__ sq,
                                            unsigned int* __restrict__ rowtab) {
    __shared__ __align__(16) unsigned short lA[2 * 128 * 32];
    __shared__ __align__(16) unsigned short lB[2 * 128 * 32];
    const int tid = threadIdx.x;
    const int wave = tid >> 6, lane = tid & 63, quad = lane >> 4, ln = lane & 15;
    const int b = blockIdx.x;
    const int xcd = b & 7, w = b >> 3;
    const int s = w >> 3, bil = w & 7;
    const int bi = xcd * 8 + bil;
    const int bj = (bi + s) & 63;
    const int i0 = bi * 128, j0 = bj * 128;
    const int m_off = (wave & 1) * 64, n_off = (wave >> 1) * 64;

    const int rl = lane >> 2;
    const int cc = ((lane & 3) - (rl >> 1)) & 3;
    unsigned short* lbase = ((wave < 2) ? lA : lB) + (wave & 1) * 2048;
    const int trow = ((wave < 2) ? i0 : j0) + (wave & 1) * 64;
    // per-stripe DMA base pointers (stripe st covers rows trow+st*16..+15)
    const unsigned short* gps[4];
#pragma unroll
    for (int st = 0; st < 4; ++st)
        gps[st] = xh + (size_t)(trow + st * 16 + rl) * DIM + cc * 8;

    int aoff[4], boff[4];
#pragma unroll
    for (int ms = 0; ms < 4; ++ms) {
        const int r = m_off + ms * 16 + ln;
        aoff[ms] = r * 32 + ((quad + (r >> 1)) & 3) * 8;
    }
#pragma unroll
    for (int ns = 0; ns < 4; ++ns) {
        const int r = n_off + ns * 16 + ln;
        boff[ns] = r * 32 + ((quad + (r >> 1)) & 3) * 8;
    }

    f32x4 acc[4][4];
#pragma unroll
    for (int a = 0; a < 4; ++a)
#pragma unroll
        for (int c = 0; c < 4; ++c) acc[a][c] = (f32x4){0.f, 0.f, 0.f, 0.f};

#pragma unroll
    for (int st = 0; st < 4; ++st)
        __builtin_amdgcn_global_load_lds(
            (const __attribute__((address_space(1))) void*)gps[st],
            (__attribute__((address_space(3))) void*)(lbase + st * 512), 16, 0, 0);

#pragma unroll
    for (int kt = 0; kt < 16; ++kt) {
        __syncthreads();
        const int cur = (kt & 1) * 4096;  // compile-time after unroll
        if (kt < 15) {
            const int nxt = ((kt + 1) & 1) * 4096;
#pragma unroll
            for (int st = 0; st < 4; ++st)
                __builtin_amdgcn_global_load_lds(
                    (const __attribute__((address_space(1))) void*)(gps[st] + (kt + 1) * 32),
                    (__attribute__((address_space(3))) void*)(lbase + nxt + st * 512),
                    16, 0, 0);
        }
        bf16x8 ah[4], bh[4];
#pragma unroll
        for (int ms = 0; ms < 4; ++ms)
            ah[ms] = *(const bf16x8*)(lA + cur + aoff[ms]);
#pragma unroll
        for (int ns = 0; ns < 4; ++ns)
            bh[ns] = *(const bf16x8*)(lB + cur + boff[ns]);
#pragma unroll
        for (int ms = 0; ms < 4; ++ms)
#pragma unroll
            for (int ns = 0; ns < 4; ++ns)
                acc[ms][ns] = __builtin_amdgcn_mfma_f32_16x16x32_bf16(
                    ah[ms], bh[ns], acc[ms][ns], 0, 0, 0);
    }

    // ---- epilogue: u32-packed top-2; scores provably positive -> pkey ----
    const bool diag = (i0 == j0);
    float sqj[4];
#pragma unroll
    for (int ns = 0; ns < 4; ++ns) sqj[ns] = sq[j0 + n_off + ns * 16 + ln];
    float sqi[4][4];
#pragma unroll
    for (int ms = 0; ms < 4; ++ms)
#pragma unroll
        for (int v = 0; v < 4; ++v)
            sqi[ms][v] = sq[i0 + m_off + ms * 16 + quad * 4 + v];

#pragma unroll
    for (int ms = 0; ms < 4; ++ms)
#pragma unroll
        for (int v = 0; v < 4; ++v) {
            const int gi = i0 + m_off + ms * 16 + quad * 4 + v;
            unsigned int pk[4];
#pragma unroll
            for (int ns = 0; ns < 4; ++ns) {
                const int gj = j0 + n_off + ns * 16 + ln;
                float d2 = fmaf(-2.f, acc[ms][ns][v], sqj[ns]);
                if (diag && gj == gi) d2 = __builtin_inff();
                pk[ns] = (pkey(d2) & KMASK) | (unsigned int)gj;
            }
            unsigned int m1 = minu(minu(pk[0], pk[1]), minu(pk[2], pk[3]));
#pragma unroll
            for (int d = 1; d < 16; d <<= 1) m1 = minu(m1, __shfl_xor(m1, d));
            unsigned int m2 = 0xFFFFFFFFu;
#pragma unroll
            for (int ns = 0; ns < 4; ++ns)
                m2 = minu(m2, pk[ns] == m1 ? 0xFFFFFFFFu : pk[ns]);
#pragma unroll
            for (int d = 1; d < 16; d <<= 1) m2 = minu(m2, __shfl_xor(m2, d));
            if (ln == 0) {
                const size_t base = ((size_t)gi * NSLOT + (s * 2 + (wave >> 1))) * 2;
                rowtab[base] = m1;
                rowtab[base + 1] = m2;
            }
        }
    if (s > 0) {
#pragma unroll
        for (int ns = 0; ns < 4; ++ns) {
            const int gj = j0 + n_off + ns * 16 + ln;
            unsigned int pk[16];
#pragma unroll
            for (int ms = 0; ms < 4; ++ms)
#pragma unroll
                for (int v = 0; v < 4; ++v) {
                    const int gi = i0 + m_off + ms * 16 + quad * 4 + v;
                    const float d2 = fmaf(-2.f, acc[ms][ns][v], sqi[ms][v]);
                    pk[ms * 4 + v] = (pkey(d2) & KMASK) | (unsigned int)gi;
                }
            unsigned int m1 = pk[0];
#pragma unroll
            for (int t = 1; t < 16; ++t) m1 = minu(m1, pk[t]);
            m1 = minu(m1, __shfl_xor(m1, 16));
            m1 = minu(m1, __shfl_xor(m1, 32));
            unsigned int m2 = 0xFFFFFFFFu;
#pragma unroll
            for (int t = 0; t < 16; ++t)
                m2 = minu(m2, pk[t] == m1 ? 0xFFFFFFFFu : pk[t]);
            m2 = minu(m2, __shfl_xor(m2, 16));
            m2 = minu(m2, __shfl_xor(m2, 32));
            if (quad == 0) {
                const size_t base =
                    ((size_t)gj * NSLOT + (66 + (s - 1) * 2 + (wave & 1))) * 2;
                rowtab[base] = m1;
                rowtab[base + 1] = m2;
            }
        }
    }
}

// ---------------------------------------------------------------- k_refine
__global__ __launch_bounds__(256) void k_refine(const unsigned int* __restrict__ rowtab,
                                                const float* __restrict__ xs,
                                                const float* __restrict__ sq,
                                                unsigned long long* __restrict__ nn) {
    __shared__ unsigned int clist[4][64];
    __shared__ int ccnt[4];
    const int wave = threadIdx.x >> 6, lane = threadIdx.x & 63;
    const int row = blockIdx.x * 4 + wave;
    if (lane == 0) ccnt[wave] = 0;
    __syncthreads();

    unsigned int vals[5];
    int nv = 0;
    unsigned int best = 0xFFFFFFFFu;
    for (int i = lane; i < NSLOT * 2; i += 64) {
        const unsigned int v = rowtab[(size_t)row * NSLOT * 2 + i];
        vals[nv++] = v;
        best = minu(best, v);
    }
#pragma unroll
    for (int d = 1; d < 64; d <<= 1) best = minu(best, __shfl_xor(best, d));

    const float dmin = unfkey(best & KMASK);
    const unsigned int tkey = fkey(dmin + 4.0f);
    for (int k = 0; k < nv; ++k)
        if ((vals[k] & KMASK) < tkey) {
            const int p = atomicAdd(&ccnt[wave], 1);
            if (p < 64) clist[wave][p] = vals[k] & 8191u;
        }
    __syncthreads();
    int cnt = ccnt[wave];
    cnt = cnt > 64 ? 64 : cnt;

    const float4* xi = (const float4*)(xs + (size_t)row * DIM);
    const float4 x0 = xi[2 * lane], x1 = xi[2 * lane + 1];
    const float sqi = sq[row];
    unsigned long long bestf = ~0ull;
    for (int c = 0; c < cnt; ++c) {
        const unsigned int j = clist[wave][c];
        const float4* xj = (const float4*)(xs + (size_t)j * DIM);
        const float4 y0 = xj[2 * lane], y1 = xj[2 * lane + 1];
        float dot = 0.f;
        dot = fmaf(x0.x, y0.x, dot); dot = fmaf(x0.y, y0.y, dot);
        dot = fmaf(x0.z, y0.z, dot); dot = fmaf(x0.w, y0.w, dot);
        dot = fmaf(x1.x, y1.x, dot); dot = fmaf(x1.y, y1.y, dot);
        dot = fmaf(x1.z, y1.z, dot); dot = fmaf(x1.w, y1.w, dot);
#pragma unroll
        for (int d = 1; d < 64; d <<= 1) dot += __shfl_xor(dot, d);
        const float d2 = sqi + sq[j] - 2.f * dot;
        const unsigned long long pk = (((unsigned long long)fkey(d2)) << 32) | j;
        bestf = min64(bestf, pk);
    }
    if (lane == 0) nn[row] = bestf;
}

// ---------------------------------------------------------------- k_mid
__global__ __launch_bounds__(256) void k_mid(const float* __restrict__ P,
                                             const unsigned long long* __restrict__ nn,
                                             const float* __restrict__ b1,
                                             const float* __restrict__ W2,
                                             const float* __restrict__ b2,
                                             const float* __restrict__ W3,
                                             const float* __restrict__ b3,
                                             const float* __restrict__ D1,
                                             const float* __restrict__ d1,
                                             const float* __restrict__ D2,
                                             const float* __restrict__ d2,
                                             float* __restrict__ out_zs,
                                             float* __restrict__ G2) {
    __shared__ float W2T[64 * 32], W3T[32 * 32], D1T[32 * 32], D2T[32 * 64];
    __shared__ float b2f[32], b3f[32], d1f[32], d2f[64];
    const int tid = threadIdx.x;
    for (int t = tid; t < 2048; t += 256) { int o = t >> 6, k = t & 63; W2T[k * 32 + o] = W2[t]; }
    for (int t = tid; t < 1024; t += 256) { int o = t >> 5, k = t & 31; W3T[k * 32 + o] = W3[t]; }
    for (int t = tid; t < 1024; t += 256) { int o = t >> 5, k = t & 31; D1T[k * 32 + o] = D1[t]; }
    for (int t = tid; t < 2048; t += 256) { int o = t >> 5, k = t & 31; D2T[k * 64 + o] = D2[t]; }
    if (tid < 32) b2f[tid] = b2[tid];
    else if (tid < 64) b3f[tid - 32] = b3[tid - 32];
    else if (tid < 96) d1f[tid - 64] = d1[tid - 64];
    else if (tid < 160) d2f[tid - 96] = d2[tid - 96];
    __syncthreads();

    const int wave = tid >> 6, lane = tid & 63;
    const int wgid = blockIdx.x * 4 + wave;  // 0..4095
    const int o32 = lane & 31;
    const float b1v = b1[lane];
    for (int r = 0; r < 2; ++r) {
        const int row = wgid + r * 4096;
        const unsigned int nnr = (unsigned int)(nn[row] & 0xFFFFFFFFull) & 8191u;
        const float pr = P[(size_t)row * 64 + lane];
        const float p0 = P[(size_t)nnr * 64 + lane];
        const float a1 = p0 + b1v;
        const float u1 = pr - p0;
        const float h1 = fmaxf(a1, 0.f);
        const float th1 = (a1 > 0.f) ? u1 : 0.f;
        float a2 = b2f[o32], u2 = 0.f;
#pragma unroll
        for (int k = 0; k < 64; ++k) {
            const float h = __shfl(h1, k);
            const float t = __shfl(th1, k);
            const float w = W2T[k * 32 + o32];
            a2 = fmaf(h, w, a2);
            u2 = fmaf(t, w, u2);
        }
        const float s = fmaxf(a2, 0.f) + ((a2 > 0.f) ? u2 : 0.f);
        float z = b3f[o32];
#pragma unroll
        for (int k = 0; k < 32; ++k) z = fmaf(__shfl(s, k), W3T[k * 32 + o32], z);
        if (lane < 32) out_zs[(size_t)row * 32 + lane] = z;
        float g1 = d1f[o32];
#pragma unroll
        for (int k = 0; k < 32; ++k) g1 = fmaf(__shfl(z, k), D1T[k * 32 + o32], g1);
        g1 = fmaxf(g1, 0.f);
        float g2 = d2f[lane];
#pragma unroll
        for (int k = 0; k < 32; ++k) g2 = fmaf(__shfl(g1, k), D2T[k * 64 + lane], g2);
        g2 = fmaxf(g2, 0.f);
        G2[(size_t)row * 64 + lane] = g2;
    }
}

// ---------------------------------------------------------------- k_dec
__global__ __launch_bounds__(256) void k_dec(const float* __restrict__ G2,
                                             const float* __restrict__ D3,
                                             const float* __restrict__ d3,
                                             float* __restrict__ xhat) {
    __shared__ __align__(16) unsigned short lGh[128 * 64], lGl[128 * 64];
    __shared__ __align__(16) unsigned short lDh[128 * 64], lDl[128 * 64];
    const int tid = threadIdx.x, wave = tid >> 6, lane = tid & 63, quad = lane >> 4,
              ln = lane & 15;
    const int i0 = blockIdx.x * 128, nbase = blockIdx.y * 128;
    const int m_off = (wave & 1) * 64, n_off = (wave >> 1) * 64;
#pragma unroll
    for (int r = 0; r < 4; ++r) {
        const int g = r * 256 + tid;
        const int row = g >> 3, cIdx = g & 7, half = cIdx >> 2, cc = cIdx & 3;
        const int wofs = row * 64 + half * 32 + ((cc + (row >> 1)) & 3) * 8;
        {
            const float* src = G2 + (size_t)(i0 + row) * 64 + cIdx * 8;
            const float4 f0 = *(const float4*)src, f1 = *(const float4*)(src + 4);
            float v[8] = {f0.x, f0.y, f0.z, f0.w, f1.x, f1.y, f1.z, f1.w};
            u16x8 h8, l8;
            split2(v, h8, l8);
            *(u16x8*)(lGh + wofs) = h8;
            *(u16x8*)(lGl + wofs) = l8;
        }
        {
            const float* src = D3 + (size_t)(nbase + row) * 64 + cIdx * 8;
            const float4 f0 = *(const float4*)src, f1 = *(const float4*)(src + 4);
            float v[8] = {f0.x, f0.y, f0.z, f0.w, f1.x, f1.y, f1.z, f1.w};
            u16x8 h8, l8;
            split2(v, h8, l8);
            *(u16x8*)(lDh + wofs) = h8;
            *(u16x8*)(lDl + wofs) = l8;
        }
    }
    __syncthreads();
    f32x4 acc[4][4];
#pragma unroll
    for (int a = 0; a < 4; ++a)
#pragma unroll
        for (int c = 0; c < 4; ++c) acc[a][c] = (f32x4){0.f, 0.f, 0.f, 0.f};
#pragma unroll
    for (int kk = 0; kk < 2; ++kk) {
        bf16x8 ah[4], al[4], bh[4], bl[4];
#pragma unroll
        for (int ms = 0; ms < 4; ++ms) {
            const int ar = m_off + ms * 16 + ln;
            const int aofs = ar * 64 + kk * 32 + ((quad + (ar >> 1)) & 3) * 8;
            ah[ms] = *(const bf16x8*)(lGh + aofs);
            al[ms] = *(const bf16x8*)(lGl + aofs);
        }
#pragma unroll
        for (int ns = 0; ns < 4; ++ns) {
            const int br = n_off + ns * 16 + ln;
            const int bofs = br * 64 + kk * 32 + ((quad + (br >> 1)) & 3) * 8;
            bh[ns] = *(const bf16x8*)(lDh + bofs);
            bl[ns] = *(const bf16x8*)(lDl + bofs);
        }
#pragma unroll
        for (int ms = 0; ms < 4; ++ms)
#pragma unroll
            for (int ns = 0; ns < 4; ++ns) {
                acc[ms][ns] = __builtin_amdgcn_mfma_f32_16x16x32_bf16(
                    ah[ms], bh[ns], acc[ms][ns], 0, 0, 0);
                acc[ms][ns] = __builtin_amdgcn_mfma_f32_16x16x32_bf16(
                    ah[ms], bl[ns], acc[ms][ns], 0, 0, 0);
                acc[ms][ns] = __builtin_amdgcn_mfma_f32_16x16x32_bf16(
                    al[ms], bh[ns], acc[ms][ns], 0, 0, 0);
            }
    }
    float d3f[4];
#pragma unroll
    for (int ns = 0; ns < 4; ++ns) d3f[ns] = d3[nbase + n_off + ns * 16 + ln];
#pragma unroll
    for (int ms = 0; ms < 4; ++ms)
#pragma unroll
        for (int ns = 0; ns < 4; ++ns)
#pragma unroll
            for (int v = 0; v < 4; ++v) {
                const int m = m_off + ms * 16 + quad * 4 + v;
                const int n = n_off + ns * 16 + ln;
                xhat[(size_t)(i0 + m) * DIM + nbase + n] = acc[ms][ns][v] + d3f[ns];
            }
}

extern "C" void kernel_launch(void* const* d_in, const int* in_sizes, int n_in,
                              void* d_out, int out_size, void* d_ws, size_t ws_size,
                              hipStream_t stream) {
    const float* xs = (const float*)d_in[0];
    const float* W1 = (const float*)d_in[1];
    const float* b1 = (const float*)d_in[2];
    const float* W2 = (const float*)d_in[3];
    const float* b2 = (const float*)d_in[4];
    const float* W3 = (const float*)d_in[5];
    const float* b3 = (const float*)d_in[6];
    const float* D1 = (const float*)d_in[7];
    const float* d1 = (const float*)d_in[8];
    const float* D2 = (const float*)d_in[9];
    const float* d2 = (const float*)d_in[10];
    const float* D3 = (const float*)d_in[11];
    const float* d3 = (const float*)d_in[12];

    // ws (12.7 MB, proven-safe layout): sq | nn | xs_hi | P | G2
    char* ws = (char*)d_ws;
    float* sq = (float*)(ws);                                     // 32 KB
    unsigned long long* nn = (unsigned long long*)(ws + 32768);   // 64 KB
    unsigned short* xs_hi = (unsigned short*)(ws + 131072);       // 8 MB
    float* P = (float*)(ws + 8519680);                            // 2 MB
    float* G2 = (float*)(ws + 10616832);                          // 2 MB

    float* xhat = (float*)d_out;
    float* zs = (float*)d_out + (size_t)NROWS * DIM;
    // rowtab scratch (u32, 8.5 MB) lives in d_out's dead space
    unsigned int* rowtab = (unsigned int*)d_out;

    hipLaunchKernelGGL(k_prep_p, dim3(2176), dim3(256), 0, stream, xs, xs_hi, sq, W1, P);
    hipLaunchKernelGGL(k_nn, dim3(2112), dim3(256), 0, stream, xs_hi, sq, rowtab);
    hipLaunchKernelGGL(k_refine, dim3(2048), dim3(256), 0, stream, rowtab, xs, sq, nn);
    hipLaunchKernelGGL(k_mid, dim3(1024), dim3(256), 0, stream, P, nn, b1, W2, b2, W3,
                       b3, D1, d1, D2, d2, zs, G2);
    hipLaunchKernelGGL(k_dec, dim3(64, 4), dim3(256), 0, stream, G2, D3, d3, xhat);
}

// Round 17
// 236.586 us; speedup vs baseline: 1.2889x; 1.0313x over previous
//
#include <hip/hip_runtime.h>
#include <hip/hip_bf16.h>

#define NROWS 8192
#define DIM 512
#define NSLOT 130  // per-row top-2 slots: 66 row-side + 64 col-side
#define KMASK 0xFFFFE000u  // top-19 key bits; low 13 = index

typedef __attribute__((ext_vector_type(8))) short bf16x8;
typedef __attribute__((ext_vector_type(4))) float f32x4;
typedef __attribute__((ext_vector_type(8))) unsigned short u16x8;

__device__ __forceinline__ float bf2f(unsigned short u) {
    return __uint_as_float(((unsigned int)u) << 16);
}
__device__ __forceinline__ unsigned short f2bf(float f) {
    unsigned int b = __float_as_uint(f);
    return (unsigned short)((b + 0x7FFFu + ((b >> 16) & 1u)) >> 16);
}
// fp32 -> e4m3fn (RNE, FTZ below 2^-6; |x| < 6 assumed -> no overflow)
__device__ __forceinline__ unsigned char f2e4m3(float x) {
    unsigned int u = __float_as_uint(x);
    unsigned int sg = (u >> 24) & 0x80u;
    if (fabsf(x) < 0.015625f) return (unsigned char)sg;
    unsigned int au = u & 0x7FFFFFFFu;
    au += 0x7FFFFu + ((au >> 20) & 1u);  // RNE to 3 mantissa bits
    const unsigned int e = (au >> 23) - 120u;  // rebias 127 -> 7
    const unsigned int m = (au >> 20) & 7u;
    return (unsigned char)(sg | (e << 3) | m);
}
// monotone float->uint key (general form; pkey for provably-positive vals)
__device__ __forceinline__ unsigned int fkey(float f) {
    unsigned int b = __float_as_uint(f);
    return (b & 0x80000000u) ? ~b : (b | 0x80000000u);
}
__device__ __forceinline__ unsigned int pkey(float f) {
    return __float_as_uint(f) | 0x80000000u;
}
__device__ __forceinline__ float unfkey(unsigned int u) {
    unsigned int b = (u & 0x80000000u) ? (u ^ 0x80000000u) : ~u;
    return __uint_as_float(b);
}
__device__ __forceinline__ unsigned int minu(unsigned int a, unsigned int b) {
    return a < b ? a : b;
}
__device__ __forceinline__ unsigned long long min64(unsigned long long a,
                                                    unsigned long long b) {
    return a < b ? a : b;
}

// helper: 3-way bf16 split
__device__ __forceinline__ void split3(const float* v, u16x8& h8, u16x8& m8, u16x8& l8) {
#pragma unroll
    for (int j = 0; j < 8; ++j) {
        const float x = v[j];
        const unsigned short h = f2bf(x);
        const float r1 = x - bf2f(h);
        const unsigned short m = f2bf(r1);
        const float r2 = r1 - bf2f(m);
        h8[j] = h; m8[j] = m; l8[j] = f2bf(r2);
    }
}
// helper: 2-way split
__device__ __forceinline__ void split2(const float* v, u16x8& h8, u16x8& l8) {
#pragma unroll
    for (int j = 0; j < 8; ++j) {
        const float x = v[j];
        const unsigned short h = f2bf(x);
        h8[j] = h; l8[j] = f2bf(x - bf2f(h));
    }
}

// ---------------------------------------------------------------- k_prep_p
// Merged: blocks 0..2047 = prep (fp8 plane + sq); blocks 2048..2175 =
// P = xs @ W1^T via 3-way-split bf16 MFMA.
__global__ __launch_bounds__(256) void k_prep_p(const float* __restrict__ xs,
                                                unsigned char* __restrict__ x8,
                                                float* __restrict__ sq,
                                                const float* __restrict__ W1,
                                                float* __restrict__ P) {
    __shared__ __align__(16) unsigned short lAh[64 * 32], lAm[64 * 32], lAl[64 * 32];
    __shared__ __align__(16) unsigned short lWh[64 * 32], lWm[64 * 32], lWl[64 * 32];
    const int tid = threadIdx.x;
    if (blockIdx.x < 2048) {
        const int wave = tid >> 6, lane = tid & 63;
        const int row = blockIdx.x * 4 + wave;
        const float4* xr = (const float4*)(xs + (size_t)row * DIM);
        const float4 a = xr[2 * lane], b = xr[2 * lane + 1];
        float v[8] = {a.x, a.y, a.z, a.w, b.x, b.y, b.z, b.w};
        unsigned long long pk8 = 0ull;
        float s = 0.f;
#pragma unroll
        for (int i = 0; i < 8; ++i) {
            pk8 |= ((unsigned long long)f2e4m3(v[i])) << (8 * i);
            s = fmaf(v[i], v[i], s);
        }
        *(unsigned long long*)(x8 + (size_t)row * DIM + lane * 8) = pk8;
#pragma unroll
        for (int d = 32; d; d >>= 1) s += __shfl_xor(s, d);
        if (lane == 0) sq[row] = s;
        return;
    }
    // ---- k_p body ----
    const int wave = tid >> 6, lane = tid & 63, quad = lane >> 4, ln = lane & 15;
    const int i0 = (blockIdx.x - 2048) * 64;
    const int row = tid >> 2, c = tid & 3;
    const int wofs = row * 32 + ((c + (row >> 1)) & 3) * 8;

    f32x4 acc[4];
#pragma unroll
    for (int ns = 0; ns < 4; ++ns) acc[ns] = (f32x4){0.f, 0.f, 0.f, 0.f};

    const int ar = wave * 16 + ln;
    const int aofs = ar * 32 + ((quad + (ar >> 1)) & 3) * 8;
    int bofs[4];
#pragma unroll
    for (int ns = 0; ns < 4; ++ns) {
        const int br = ns * 16 + ln;
        bofs[ns] = br * 32 + ((quad + (br >> 1)) & 3) * 8;
    }

    for (int kt = 0; kt < 16; ++kt) {
        __syncthreads();
        {
            const float* src = xs + (size_t)(i0 + row) * DIM + kt * 32 + c * 8;
            const float4 f0 = *(const float4*)src, f1 = *(const float4*)(src + 4);
            float v[8] = {f0.x, f0.y, f0.z, f0.w, f1.x, f1.y, f1.z, f1.w};
            u16x8 h8, m8, l8;
            split3(v, h8, m8, l8);
            *(u16x8*)(lAh + wofs) = h8;
            *(u16x8*)(lAm + wofs) = m8;
            *(u16x8*)(lAl + wofs) = l8;
        }
        {
            const float* src = W1 + (size_t)row * DIM + kt * 32 + c * 8;
            const float4 f0 = *(const float4*)src, f1 = *(const float4*)(src + 4);
            float v[8] = {f0.x, f0.y, f0.z, f0.w, f1.x, f1.y, f1.z, f1.w};
            u16x8 h8, m8, l8;
            split3(v, h8, m8, l8);
            *(u16x8*)(lWh + wofs) = h8;
            *(u16x8*)(lWm + wofs) = m8;
            *(u16x8*)(lWl + wofs) = l8;
        }
        __syncthreads();
        const bf16x8 ah = *(const bf16x8*)(lAh + aofs);
        const bf16x8 am = *(const bf16x8*)(lAm + aofs);
        const bf16x8 al = *(const bf16x8*)(lAl + aofs);
#pragma unroll
        for (int ns = 0; ns < 4; ++ns) {
            const bf16x8 bh = *(const bf16x8*)(lWh + bofs[ns]);
            const bf16x8 bm = *(const bf16x8*)(lWm + bofs[ns]);
            const bf16x8 bl = *(const bf16x8*)(lWl + bofs[ns]);
            acc[ns] = __builtin_amdgcn_mfma_f32_16x16x32_bf16(ah, bh, acc[ns], 0, 0, 0);
            acc[ns] = __builtin_amdgcn_mfma_f32_16x16x32_bf16(ah, bm, acc[ns], 0, 0, 0);
            acc[ns] = __builtin_amdgcn_mfma_f32_16x16x32_bf16(am, bh, acc[ns], 0, 0, 0);
            acc[ns] = __builtin_amdgcn_mfma_f32_16x16x32_bf16(am, bm, acc[ns], 0, 0, 0);
            acc[ns] = __builtin_amdgcn_mfma_f32_16x16x32_bf16(ah, bl, acc[ns], 0, 0, 0);
            acc[ns] = __builtin_amdgcn_mfma_f32_16x16x32_bf16(al, bh, acc[ns], 0, 0, 0);
        }
    }
#pragma unroll
    for (int ns = 0; ns < 4; ++ns)
#pragma unroll
        for (int v = 0; v < 4; ++v)
            P[(size_t)(i0 + wave * 16 + quad * 4 + v) * 64 + ns * 16 + ln] = acc[ns][v];
}

// ---------------------------------------------------------------- k_nn
// fp8 candidate pass, BK=64, 8 unrolled kt iterations, DMA double-buffer
// (32 KB LDS total). Pair-granular swizzle: row r stores global 16B-pair g at
// pair position (g + ((r>>1)&3)) & 3  -> DMA landing is linear-contiguous per
// lane AND all ds_read_b64 fragment reads are 2-way (free). u32 top-2 epilogue.
__global__ __launch_bounds__(256) void k_nn(const unsigned char* __restrict__ x8,
                                            const float* __restrict__ sq,
                                            unsigned int* __restrict__ rowtab) {
    __shared__ __align__(16) unsigned char lA[2 * 8192];
    __shared__ __align__(16) unsigned char lB[2 * 8192];
    const int tid = threadIdx.x;
    const int wave = tid >> 6, lane = tid & 63, quad = lane >> 4, ln = lane & 15;
    const int b = blockIdx.x;
    const int xcd = b & 7, w = b >> 3;
    const int s = w >> 3, bil = w & 7;
    const int bi = xcd * 8 + bil;
    const int bj = (bi + s) & 63;
    const int i0 = bi * 128, j0 = bj * 128;
    const int m_off = (wave & 1) * 64, n_off = (wave >> 1) * 64;

    // staging: 4 lanes/row (64 B), rl=lane>>2, landing pair qp=lane&3 holds
    // global pair sp = (qp - (rl>>1)) & 3   [(r>>1)&3 == (rl>>1)&3, 64|trow]
    const int rl = lane >> 2;
    const int sp = ((lane & 3) - (rl >> 1)) & 3;
    unsigned char* mybuf = ((wave < 2) ? lA : lB) + (wave & 1) * 4096;
    const int trow = ((wave < 2) ? i0 : j0) + (wave & 1) * 64;
    const unsigned char* gps[4];
#pragma unroll
    for (int st = 0; st < 4; ++st)
        gps[st] = x8 + (size_t)(trow + st * 16 + rl) * DIM + sp * 16;

    // fragment read offsets: chunk c = ks*4+quad; pos = 2*((c>>1 + (r>>1)&3)&3) + (c&1)
    int aoff[4][2], boff[4][2];
#pragma unroll
    for (int ms = 0; ms < 4; ++ms) {
        const int r = m_off + ms * 16 + ln;
        const int sw = (r >> 1) & 3;
#pragma unroll
        for (int ks = 0; ks < 2; ++ks) {
            const int c = ks * 4 + quad;
            aoff[ms][ks] = r * 64 + (2 * (((c >> 1) + sw) & 3) + (c & 1)) * 8;
        }
    }
#pragma unroll
    for (int ns = 0; ns < 4; ++ns) {
        const int r = n_off + ns * 16 + ln;
        const int sw = (r >> 1) & 3;
#pragma unroll
        for (int ks = 0; ks < 2; ++ks) {
            const int c = ks * 4 + quad;
            boff[ns][ks] = r * 64 + (2 * (((c >> 1) + sw) & 3) + (c & 1)) * 8;
        }
    }

    f32x4 acc[4][4];
#pragma unroll
    for (int a = 0; a < 4; ++a)
#pragma unroll
        for (int c = 0; c < 4; ++c) acc[a][c] = (f32x4){0.f, 0.f, 0.f, 0.f};

    // preload kt=0 into buf0
#pragma unroll
    for (int st = 0; st < 4; ++st)
        __builtin_amdgcn_global_load_lds(
            (const __attribute__((address_space(1))) void*)gps[st],
            (__attribute__((address_space(3))) void*)(mybuf + st * 1024), 16, 0, 0);

#pragma unroll
    for (int kt = 0; kt < 8; ++kt) {
        __syncthreads();  // drains DMA filling buf[kt&1]; prior reads done
        const int cur = (kt & 1) * 8192;
        if (kt < 7) {
            const int nxt = ((kt + 1) & 1) * 8192;
#pragma unroll
            for (int st = 0; st < 4; ++st)
                __builtin_amdgcn_global_load_lds(
                    (const __attribute__((address_space(1))) void*)(gps[st] + (kt + 1) * 64),
                    (__attribute__((address_space(3))) void*)(mybuf + nxt + st * 1024),
                    16, 0, 0);
        }
        long av[4][2], bv[4][2];
#pragma unroll
        for (int ms = 0; ms < 4; ++ms) {
            av[ms][0] = *(const long*)(lA + cur + aoff[ms][0]);
            av[ms][1] = *(const long*)(lA + cur + aoff[ms][1]);
        }
#pragma unroll
        for (int ns = 0; ns < 4; ++ns) {
            bv[ns][0] = *(const long*)(lB + cur + boff[ns][0]);
            bv[ns][1] = *(const long*)(lB + cur + boff[ns][1]);
        }
#pragma unroll
        for (int ks = 0; ks < 2; ++ks)
#pragma unroll
            for (int ms = 0; ms < 4; ++ms)
#pragma unroll
                for (int ns = 0; ns < 4; ++ns)
                    acc[ms][ns] = __builtin_amdgcn_mfma_f32_16x16x32_fp8_fp8(
                        av[ms][ks], bv[ns][ks], acc[ms][ns], 0, 0, 0);
    }

    // ---- epilogue: u32-packed top-2; scores provably positive -> pkey ----
    const bool diag = (i0 == j0);
    float sqj[4];
#pragma unroll
    for (int ns = 0; ns < 4; ++ns) sqj[ns] = sq[j0 + n_off + ns * 16 + ln];
    float sqi[4][4];
#pragma unroll
    for (int ms = 0; ms < 4; ++ms)
#pragma unroll
        for (int v = 0; v < 4; ++v)
            sqi[ms][v] = sq[i0 + m_off + ms * 16 + quad * 4 + v];

#pragma unroll
    for (int ms = 0; ms < 4; ++ms)
#pragma unroll
        for (int v = 0; v < 4; ++v) {
            const int gi = i0 + m_off + ms * 16 + quad * 4 + v;
            unsigned int pk[4];
#pragma unroll
            for (int ns = 0; ns < 4; ++ns) {
                const int gj = j0 + n_off + ns * 16 + ln;
                float d2 = fmaf(-2.f, acc[ms][ns][v], sqj[ns]);
                if (diag && gj == gi) d2 = __builtin_inff();
                pk[ns] = (pkey(d2) & KMASK) | (unsigned int)gj;
            }
            unsigned int m1 = minu(minu(pk[0], pk[1]), minu(pk[2], pk[3]));
#pragma unroll
            for (int d = 1; d < 16; d <<= 1) m1 = minu(m1, __shfl_xor(m1, d));
            unsigned int m2 = 0xFFFFFFFFu;
#pragma unroll
            for (int ns = 0; ns < 4; ++ns)
                m2 = minu(m2, pk[ns] == m1 ? 0xFFFFFFFFu : pk[ns]);
#pragma unroll
            for (int d = 1; d < 16; d <<= 1) m2 = minu(m2, __shfl_xor(m2, d));
            if (ln == 0) {
                const size_t base = ((size_t)gi * NSLOT + (s * 2 + (wave >> 1))) * 2;
                rowtab[base] = m1;
                rowtab[base + 1] = m2;
            }
        }
    if (s > 0) {
#pragma unroll
        for (int ns = 0; ns < 4; ++ns) {
            const int gj = j0 + n_off + ns * 16 + ln;
            unsigned int pk[16];
#pragma unroll
            for (int ms = 0; ms < 4; ++ms)
#pragma unroll
                for (int v = 0; v < 4; ++v) {
                    const int gi = i0 + m_off + ms * 16 + quad * 4 + v;
                    const float d2 = fmaf(-2.f, acc[ms][ns][v], sqi[ms][v]);
                    pk[ms * 4 + v] = (pkey(d2) & KMASK) | (unsigned int)gi;
                }
            unsigned int m1 = pk[0];
#pragma unroll
            for (int t = 1; t < 16; ++t) m1 = minu(m1, pk[t]);
            m1 = minu(m1, __shfl_xor(m1, 16));
            m1 = minu(m1, __shfl_xor(m1, 32));
            unsigned int m2 = 0xFFFFFFFFu;
#pragma unroll
            for (int t = 0; t < 16; ++t)
                m2 = minu(m2, pk[t] == m1 ? 0xFFFFFFFFu : pk[t]);
            m2 = minu(m2, __shfl_xor(m2, 16));
            m2 = minu(m2, __shfl_xor(m2, 32));
            if (quad == 0) {
                const size_t base =
                    ((size_t)gj * NSLOT + (66 + (s - 1) * 2 + (wave & 1))) * 2;
                rowtab[base] = m1;
                rowtab[base + 1] = m2;
            }
        }
    }
}

// ---------------------------------------------------------------- k_refine
// Margin widened to 12.0 for fp8 score noise (sigma ~1.3) + key quantization.
__global__ __launch_bounds__(256) void k_refine(const unsigned int* __restrict__ rowtab,
                                                const float* __restrict__ xs,
                                                const float* __restrict__ sq,
                                                unsigned long long* __restrict__ nn) {
    __shared__ unsigned int clist[4][64];
    __shared__ int ccnt[4];
    const int wave = threadIdx.x >> 6, lane = threadIdx.x & 63;
    const int row = blockIdx.x * 4 + wave;
    if (lane == 0) ccnt[wave] = 0;
    __syncthreads();

    unsigned int vals[5];
    int nv = 0;
    unsigned int best = 0xFFFFFFFFu;
    for (int i = lane; i < NSLOT * 2; i += 64) {
        const unsigned int v = rowtab[(size_t)row * NSLOT * 2 + i];
        vals[nv++] = v;
        best = minu(best, v);
    }
#pragma unroll
    for (int d = 1; d < 64; d <<= 1) best = minu(best, __shfl_xor(best, d));

    const float dmin = unfkey(best & KMASK);
    const unsigned int tkey = fkey(dmin + 12.0f);
    for (int k = 0; k < nv; ++k)
        if ((vals[k] & KMASK) < tkey) {
            const int p = atomicAdd(&ccnt[wave], 1);
            if (p < 64) clist[wave][p] = vals[k] & 8191u;
        }
    __syncthreads();
    int cnt = ccnt[wave];
    cnt = cnt > 64 ? 64 : cnt;

    const float4* xi = (const float4*)(xs + (size_t)row * DIM);
    const float4 x0 = xi[2 * lane], x1 = xi[2 * lane + 1];
    const float sqi = sq[row];
    unsigned long long bestf = ~0ull;
    for (int c = 0; c < cnt; ++c) {
        const unsigned int j = clist[wave][c];
        const float4* xj = (const float4*)(xs + (size_t)j * DIM);
        const float4 y0 = xj[2 * lane], y1 = xj[2 * lane + 1];
        float dot = 0.f;
        dot = fmaf(x0.x, y0.x, dot); dot = fmaf(x0.y, y0.y, dot);
        dot = fmaf(x0.z, y0.z, dot); dot = fmaf(x0.w, y0.w, dot);
        dot = fmaf(x1.x, y1.x, dot); dot = fmaf(x1.y, y1.y, dot);
        dot = fmaf(x1.z, y1.z, dot); dot = fmaf(x1.w, y1.w, dot);
#pragma unroll
        for (int d = 1; d < 64; d <<= 1) dot += __shfl_xor(dot, d);
        const float d2 = sqi + sq[j] - 2.f * dot;
        const unsigned long long pk = (((unsigned long long)fkey(d2)) << 32) | j;
        bestf = min64(bestf, pk);
    }
    if (lane == 0) nn[row] = bestf;
}

// ---------------------------------------------------------------- k_mid
__global__ __launch_bounds__(256) void k_mid(const float* __restrict__ P,
                                             const unsigned long long* __restrict__ nn,
                                             const float* __restrict__ b1,
                                             const float* __restrict__ W2,
                                             const float* __restrict__ b2,
                                             const float* __restrict__ W3,
                                             const float* __restrict__ b3,
                                             const float* __restrict__ D1,
                                             const float* __restrict__ d1,
                                             const float* __restrict__ D2,
                                             const float* __restrict__ d2,
                                             float* __restrict__ out_zs,
                                             float* __restrict__ G2) {
    __shared__ float W2T[64 * 32], W3T[32 * 32], D1T[32 * 32], D2T[32 * 64];
    __shared__ float b2f[32], b3f[32], d1f[32], d2f[64];
    const int tid = threadIdx.x;
    for (int t = tid; t < 2048; t += 256) { int o = t >> 6, k = t & 63; W2T[k * 32 + o] = W2[t]; }
    for (int t = tid; t < 1024; t += 256) { int o = t >> 5, k = t & 31; W3T[k * 32 + o] = W3[t]; }
    for (int t = tid; t < 1024; t += 256) { int o = t >> 5, k = t & 31; D1T[k * 32 + o] = D1[t]; }
    for (int t = tid; t < 2048; t += 256) { int o = t >> 5, k = t & 31; D2T[k * 64 + o] = D2[t]; }
    if (tid < 32) b2f[tid] = b2[tid];
    else if (tid < 64) b3f[tid - 32] = b3[tid - 32];
    else if (tid < 96) d1f[tid - 64] = d1[tid - 64];
    else if (tid < 160) d2f[tid - 96] = d2[tid - 96];
    __syncthreads();

    const int wave = tid >> 6, lane = tid & 63;
    const int wgid = blockIdx.x * 4 + wave;  // 0..4095
    const int o32 = lane & 31;
    const float b1v = b1[lane];
    for (int r = 0; r < 2; ++r) {
        const int row = wgid + r * 4096;
        const unsigned int nnr = (unsigned int)(nn[row] & 0xFFFFFFFFull) & 8191u;
        const float pr = P[(size_t)row * 64 + lane];
        const float p0 = P[(size_t)nnr * 64 + lane];
        const float a1 = p0 + b1v;
        const float u1 = pr - p0;
        const float h1 = fmaxf(a1, 0.f);
        const float th1 = (a1 > 0.f) ? u1 : 0.f;
        float a2 = b2f[o32], u2 = 0.f;
#pragma unroll
        for (int k = 0; k < 64; ++k) {
            const float h = __shfl(h1, k);
            const float t = __shfl(th1, k);
            const float w = W2T[k * 32 + o32];
            a2 = fmaf(h, w, a2);
            u2 = fmaf(t, w, u2);
        }
        const float s = fmaxf(a2, 0.f) + ((a2 > 0.f) ? u2 : 0.f);
        float z = b3f[o32];
#pragma unroll
        for (int k = 0; k < 32; ++k) z = fmaf(__shfl(s, k), W3T[k * 32 + o32], z);
        if (lane < 32) out_zs[(size_t)row * 32 + lane] = z;
        float g1 = d1f[o32];
#pragma unroll
        for (int k = 0; k < 32; ++k) g1 = fmaf(__shfl(z, k), D1T[k * 32 + o32], g1);
        g1 = fmaxf(g1, 0.f);
        float g2 = d2f[lane];
#pragma unroll
        for (int k = 0; k < 32; ++k) g2 = fmaf(__shfl(g1, k), D2T[k * 64 + lane], g2);
        g2 = fmaxf(g2, 0.f);
        G2[(size_t)row * 64 + lane] = g2;
    }
}

// ---------------------------------------------------------------- k_dec
__global__ __launch_bounds__(256) void k_dec(const float* __restrict__ G2,
                                             const float* __restrict__ D3,
                                             const float* __restrict__ d3,
                                             float* __restrict__ xhat) {
    __shared__ __align__(16) unsigned short lGh[128 * 64], lGl[128 * 64];
    __shared__ __align__(16) unsigned short lDh[128 * 64], lDl[128 * 64];
    const int tid = threadIdx.x, wave = tid >> 6, lane = tid & 63, quad = lane >> 4,
              ln = lane & 15;
    const int i0 = blockIdx.x * 128, nbase = blockIdx.y * 128;
    const int m_off = (wave & 1) * 64, n_off = (wave >> 1) * 64;
#pragma unroll
    for (int r = 0; r < 4; ++r) {
        const int g = r * 256 + tid;
        const int row = g >> 3, cIdx = g & 7, half = cIdx >> 2, cc = cIdx & 3;
        const int wofs = row * 64 + half * 32 + ((cc + (row >> 1)) & 3) * 8;
        {
            const float* src = G2 + (size_t)(i0 + row) * 64 + cIdx * 8;
            const float4 f0 = *(const float4*)src, f1 = *(const float4*)(src + 4);
            float v[8] = {f0.x, f0.y, f0.z, f0.w, f1.x, f1.y, f1.z, f1.w};
            u16x8 h8, l8;
            split2(v, h8, l8);
            *(u16x8*)(lGh + wofs) = h8;
            *(u16x8*)(lGl + wofs) = l8;
        }
        {
            const float* src = D3 + (size_t)(nbase + row) * 64 + cIdx * 8;
            const float4 f0 = *(const float4*)src, f1 = *(const float4*)(src + 4);
            float v[8] = {f0.x, f0.y, f0.z, f0.w, f1.x, f1.y, f1.z, f1.w};
            u16x8 h8, l8;
            split2(v, h8, l8);
            *(u16x8*)(lDh + wofs) = h8;
            *(u16x8*)(lDl + wofs) = l8;
        }
    }
    __syncthreads();
    f32x4 acc[4][4];
#pragma unroll
    for (int a = 0; a < 4; ++a)
#pragma unroll
        for (int c = 0; c < 4; ++c) acc[a][c] = (f32x4){0.f, 0.f, 0.f, 0.f};
#pragma unroll
    for (int kk = 0; kk < 2; ++kk) {
        bf16x8 ah[4], al[4], bh[4], bl[4];
#pragma unroll
        for (int ms = 0; ms < 4; ++ms) {
            const int ar = m_off + ms * 16 + ln;
            const int aofs = ar * 64 + kk * 32 + ((quad + (ar >> 1)) & 3) * 8;
            ah[ms] = *(const bf16x8*)(lGh + aofs);
            al[ms] = *(const bf16x8*)(lGl + aofs);
        }
#pragma unroll
        for (int ns = 0; ns < 4; ++ns) {
            const int br = n_off + ns * 16 + ln;
            const int bofs = br * 64 + kk * 32 + ((quad + (br >> 1)) & 3) * 8;
            bh[ns] = *(const bf16x8*)(lDh + bofs);
            bl[ns] = *(const bf16x8*)(lDl + bofs);
        }
#pragma unroll
        for (int ms = 0; ms < 4; ++ms)
#pragma unroll
            for (int ns = 0; ns < 4; ++ns) {
                acc[ms][ns] = __builtin_amdgcn_mfma_f32_16x16x32_bf16(
                    ah[ms], bh[ns], acc[ms][ns], 0, 0, 0);
                acc[ms][ns] = __builtin_amdgcn_mfma_f32_16x16x32_bf16(
                    ah[ms], bl[ns], acc[ms][ns], 0, 0, 0);
                acc[ms][ns] = __builtin_amdgcn_mfma_f32_16x16x32_bf16(
                    al[ms], bh[ns], acc[ms][ns], 0, 0, 0);
            }
    }
    float d3f[4];
#pragma unroll
    for (int ns = 0; ns < 4; ++ns) d3f[ns] = d3[nbase + n_off + ns * 16 + ln];
#pragma unroll
    for (int ms = 0; ms < 4; ++ms)
#pragma unroll
        for (int ns = 0; ns < 4; ++ns)
#pragma unroll
            for (int v = 0; v < 4; ++v) {
                const int m = m_off + ms * 16 + quad * 4 + v;
                const int n = n_off + ns * 16 + ln;
                xhat[(size_t)(i0 + m) * DIM + nbase + n] = acc[ms][ns][v] + d3f[ns];
            }
}

extern "C" void kernel_launch(void* const* d_in, const int* in_sizes, int n_in,
                              void* d_out, int out_size, void* d_ws, size_t ws_size,
                              hipStream_t stream) {
    const float* xs = (const float*)d_in[0];
    const float* W1 = (const float*)d_in[1];
    const float* b1 = (const float*)d_in[2];
    const float* W2 = (const float*)d_in[3];
    const float* b2 = (const float*)d_in[4];
    const float* W3 = (const float*)d_in[5];
    const float* b3 = (const float*)d_in[6];
    const float* D1 = (const float*)d_in[7];
    const float* d1 = (const float*)d_in[8];
    const float* D2 = (const float*)d_in[9];
    const float* d2 = (const float*)d_in[10];
    const float* D3 = (const float*)d_in[11];
    const float* d3 = (const float*)d_in[12];

    // ws: sq | nn | xs_f8 (4 MB) | P | G2   (offsets unchanged, proven-safe)
    char* ws = (char*)d_ws;
    float* sq = (float*)(ws);                                     // 32 KB
    unsigned long long* nn = (unsigned long long*)(ws + 32768);   // 64 KB
    unsigned char* xs_f8 = (unsigned char*)(ws + 131072);         // 4 MB
    float* P = (float*)(ws + 8519680);                            // 2 MB
    float* G2 = (float*)(ws + 10616832);                          // 2 MB

    float* xhat = (float*)d_out;
    float* zs = (float*)d_out + (size_t)NROWS * DIM;
    // rowtab scratch (u32, 8.5 MB) lives in d_out's dead space
    unsigned int* rowtab = (unsigned int*)d_out;

    hipLaunchKernelGGL(k_prep_p, dim3(2176), dim3(256), 0, stream, xs, xs_f8, sq, W1, P);
    hipLaunchKernelGGL(k_nn, dim3(2112), dim3(256), 0, stream, xs_f8, sq, rowtab);
    hipLaunchKernelGGL(k_refine, dim3(2048), dim3(256), 0, stream, rowtab, xs, sq, nn);
    hipLaunchKernelGGL(k_mid, dim3(1024), dim3(256), 0, stream, P, nn, b1, W2, b2, W3,
                       b3, D1, d1, D2, d2, zs, G2);
    hipLaunchKernelGGL(k_dec, dim3(64, 4), dim3(256), 0, stream, G2, D3, d3, xhat);
}